// Round 8
// baseline (2159.726 us; speedup 1.0000x reference)
//
#include <hip/hip_runtime.h>
#include <hip/hip_bf16.h>
#include <stdint.h>

#define B_   256
#define S_   256
#define DM   512
#define G4   2048
#define LAT  128
#define PR   128
#define NB   4      // batches per block -> 64 blocks

typedef __bf16 bf16x8 __attribute__((ext_vector_type(8)));
typedef float  f32x4  __attribute__((ext_vector_type(4)));

__device__ __forceinline__ bf16x8 ldg8(const __hip_bfloat16* p){
  uint4 v = *reinterpret_cast<const uint4*>(p);
  return __builtin_bit_cast(bf16x8, v);
}
__device__ __forceinline__ float sigf(float x){ return 1.f/(1.f+__expf(-x)); }
__device__ __forceinline__ float tanhft(float x){ return 1.f - 2.f/(__expf(2.f*x)+1.f); }
__device__ __forceinline__ unsigned char f2fp8(float x){
  return (unsigned char)(__builtin_amdgcn_cvt_pk_fp8_f32(x, x, 0, false) & 0xff);
}

#define BSCALE 64.f
#define ASCALE 8.f
#define DSCALE (1.f/512.f)

// ================= prep 1: W_comb[2048][16] = W_ih[:, :512] · Wcat, + folded x-bias ===========
__global__ void k_fold(const float* __restrict__ W_ih,
                       const float* __restrict__ W_cmd, const float* __restrict__ b_cmd,
                       const float* __restrict__ W_coord, const float* __restrict__ b_coord,
                       const float* __restrict__ W_head, const float* __restrict__ b_head,
                       float* __restrict__ W_comb, float* __restrict__ b_fold)
{
  const int g = blockIdx.x;      // 2048
  const int lane = threadIdx.x;  // 64
  float p[17];
  #pragma unroll
  for (int k=0;k<17;++k) p[k]=0.f;
  for (int d = lane; d < DM; d += 64){
    float w = W_ih[g*640 + d];
    #pragma unroll
    for (int c=0;c<6;++c)  p[c]    += w * W_cmd[d*6+c];
    #pragma unroll
    for (int c=0;c<8;++c)  p[6+c]  += w * W_coord[d*8+c];
    p[14] += w * W_head[d*2+0];
    p[15] += w * W_head[d*2+1];
    p[16] += w * (b_cmd[d] + b_coord[d] + b_head[d]);
  }
  #pragma unroll
  for (int k=0;k<17;++k){
    #pragma unroll
    for (int off=32; off>0; off>>=1) p[k] += __shfl_xor(p[k], off);
  }
  if (lane == 0){
    #pragma unroll
    for (int k=0;k<16;++k) W_comb[g*16+k] = p[k];
    b_fold[g] = p[16];
  }
}

// ================= prep 2: gate-B fp8, scaled xBSCALE, fragment-linear ======================
__global__ void k_bp(const float* __restrict__ Whh, const float* __restrict__ W_comb,
                     unsigned char* __restrict__ Bp)
{
  const int flat = blockIdx.x*256 + threadIdx.x;   // 1280 blocks -> 327680
  const int j   = flat & 7;
  const int l   = (flat >> 3) & 63;
  const int idx = flat >> 9;                        // n*5 + kc
  const int n   = idx / 5;
  const int kc  = idx - n*5;
  const int g   = n*16 + (l & 15);
  const int k   = kc*32 + ((l >> 4) & 3)*8 + j;
  float v = (k < 128) ? Whh[g*PR + k] : ((k < 144) ? W_comb[g*16 + (k-128)] : 0.f);
  Bp[flat] = f2fp8(BSCALE * v);
}

// ================= prep 3: W_hr bf16 fragment-linear (8 tiles) ==============================
__global__ void k_wr2(const float* __restrict__ Whr, __hip_bfloat16* __restrict__ Wr2)
{
  const int flat = blockIdx.x*256 + threadIdx.x;   // 256 blocks: 8*16*64*8 = 65536
  const int j   = flat & 7;
  const int l   = (flat >> 3) & 63;
  const int kc  = (flat >> 9) & 15;
  const int tn  = flat >> 13;                       // 0..7
  const int row = tn*16 + (l & 15);                 // p < 128
  const int d   = kc*32 + ((l >> 4) & 3)*8 + j;
  Wr2[flat] = __float2bfloat16(Whr[row*DM + d]);
}

// ================= prep 4: folded head weights W~[t][p] (coord absorbs cmd), + bias =========
__global__ void k_wout(const float* __restrict__ Wocmd, const float* __restrict__ Wocoord,
                       const float* __restrict__ bocmd, const float* __restrict__ bocoord,
                       __hip_bfloat16* __restrict__ Wh, float* __restrict__ btil)
{
  if (blockIdx.x == 8){
    const int t = threadIdx.x;
    if (t < 16){
      float bv = 0.f;
      if (t < 6) bv = bocmd[t];
      else if (t < 14){
        bv = bocoord[t-6];
        for (int k=0;k<6;++k) bv += Wocoord[(t-6)*134 + 128 + k]*bocmd[k];
      }
      btil[t] = bv;
    }
    return;
  }
  const int flat = blockIdx.x*256 + threadIdx.x;   // 0..2047
  const int j  = flat & 7;
  const int l  = (flat >> 3) & 63;
  const int kc = flat >> 9;                         // 0..3
  const int t  = l & 15;
  const int p  = kc*32 + ((l >> 4) & 3)*8 + j;
  float v = 0.f;
  if (t < 6) v = Wocmd[t*PR + p];
  else if (t < 14){
    v = Wocoord[(t-6)*134 + p];
    for (int k=0;k<6;++k) v += Wocoord[(t-6)*134 + 128 + k]*Wocmd[k*PR + p];
  }
  Wh[flat] = __float2bfloat16(v);
}

// ================= prep 5: ctxB[b][g] = b_ih+b_hh+b_fold + ctx[b]·W_ih[g,512:] (b-major) ====
__global__ void k_ctx(const float* __restrict__ context, const float* __restrict__ W_ih,
                      const float* __restrict__ b_ih, const float* __restrict__ b_hh,
                      const float* __restrict__ b_fold, float* __restrict__ ctxB)
{
  const int idx = blockIdx.x*256 + threadIdx.x;   // 2048 blocks * 256 = B_*G4
  const int b = idx >> 11;
  const int g = idx & 2047;
  float a = b_ih[g] + b_hh[g] + b_fold[g];
  const float4* cp = reinterpret_cast<const float4*>(context + b*LAT);
  const float4* wp = reinterpret_cast<const float4*>(W_ih + g*640 + DM);
  #pragma unroll 8
  for (int q=0; q<LAT/4; ++q){
    float4 c = cp[q], w = wp[q];
    a += c.x*w.x + c.y*w.y + c.z*w.z + c.w*w.w;
  }
  ctxB[idx] = a;   // [b][g]
}

// ================= fused MFMA LSTM scan: all weights on-CU, 3 barriers/step =================
__global__ __launch_bounds__(512, 2)
void k_scan(const float* __restrict__ x_std,
            const float* __restrict__ ctxB,
            const unsigned char* __restrict__ Bp,
            const __hip_bfloat16* __restrict__ Wr2,
            const __hip_bfloat16* __restrict__ Wh,
            const float* __restrict__ btil,
            const float* __restrict__ ln_g, const float* __restrict__ ln_b,
            float* __restrict__ out_cmd, float* __restrict__ out_coord)
{
  const int tid = threadIdx.x;
  const int w   = tid >> 6;        // wave 0..7
  const int l   = tid & 63;
  const int l15 = l & 15;
  const int lq  = l >> 4;          // 0..3
  const int b0  = blockIdx.x * NB;

  __shared__ __align__(16) __hip_bfloat16 Wr2L[8*8*64*8];   // 64 KB: Wr2 kc 8..15 per wave-tile
  __shared__ __align__(8)  unsigned char  Bwp[128*32*8];    // 32 KB: kc4 packed (real half only)
  __shared__ __align__(16) float ctx4[G4*NB];               // 32 KB: [g][b] f32
  __shared__ __align__(16) __hip_bfloat16 HF[NB*520];       // 4.2 KB [b][d]
  __shared__ __align__(8)  unsigned char  A8[16*168];       // 2.7 KB [b][k] fp8, rows 4-15 zero
  __shared__ __align__(16) __hip_bfloat16 HN[16*136];       // 4.4 KB [b][p], rows 4-15 zero
  __shared__ float s_m[32], s_q[32];

  // ---- gate weights kc=0..3 -> registers (128, expect AGPR) ----
  long bp[4][4][4];
  {
    const long* Bpl = reinterpret_cast<const long*>(Bp);
    #pragma unroll
    for (int dtl=0; dtl<4; ++dtl)
      #pragma unroll
      for (int gt=0; gt<4; ++gt)
        #pragma unroll
        for (int kc=0; kc<4; ++kc){
          const int n = gt*32 + w*4 + dtl;
          bp[dtl][gt][kc] = Bpl[(n*5 + kc)*64 + l];
        }
  }
  // ---- Wr2 kc 0..7 -> 32 VGPRs (once) ----
  uint4 wrr[8];
  {
    const uint4* Wr2u4 = reinterpret_cast<const uint4*>(Wr2);
    #pragma unroll
    for (int kk=0; kk<8; ++kk)
      wrr[kk] = Wr2u4[(w*16 + kk)*64 + l];
  }
  // ---- stage Wr2 kc 8..15 -> LDS ----
  {
    const uint4* Wr2u4 = reinterpret_cast<const uint4*>(Wr2);
    uint4* dst = reinterpret_cast<uint4*>(Wr2L);
    for (int i = tid; i < 4096; i += 512){
      const int widx = i >> 9;
      const int kk   = (i >> 6) & 7;
      const int ll   = i & 63;
      dst[i] = Wr2u4[(widx*16 + 8 + kk)*64 + ll];
    }
  }
  // ---- stage kc4 packed -> LDS (real half: orig lanes 0..31) ----
  {
    const long* Bpl = reinterpret_cast<const long*>(Bp);
    long* dst = reinterpret_cast<long*>(Bwp);
    for (int i = tid; i < 4096; i += 512)
      dst[i] = Bpl[((i>>5)*5 + 4)*64 + (i & 31)];
  }
  // ---- stage ctx -> LDS [g][b] f32 (coalesced reads per batch) ----
  for (int i = tid; i < G4*NB; i += 512){
    const int bb = i >> 11, g = i & 2047;
    ctx4[g*NB + bb] = ctxB[(b0+bb)*G4 + g];
  }
  // ---- zero A8 / HN (rows 4-15 stay zero forever) ----
  for (int i = tid; i < 16*168/4; i += 512) reinterpret_cast<unsigned*>(A8)[i] = 0u;
  for (int i = tid; i < 16*136/2; i += 512) reinterpret_cast<unsigned*>(HN)[i] = 0u;
  __syncthreads();
  if (tid < 64){
    const int b = tid >> 4, c = tid & 15;
    A8[b*168 + 128 + c] = f2fp8(ASCALE * x_std[(b0+b)*S_*16 + c]);   // x at s=0
  }

  const float lng = ln_g[w*16 + l15];
  const float lnb = ln_b[w*16 + l15];
  const float bb  = (l15 < 14) ? btil[l15] : 0.f;

  float c_st[4][4];   // [dtl][batch] cell state on lq==0 lanes
  #pragma unroll
  for (int q=0;q<4;++q)
    #pragma unroll
    for (int r=0;r<4;++r) c_st[q][r] = 0.f;
  __syncthreads();

  const f32x4 zz = {0.f, 0.f, 0.f, 0.f};
  const int a_off = l15*168 + lq*8;
  const long* Bwpl = reinterpret_cast<const long*>(Bwp);

  for (int s = 0; s < S_; ++s){
    // ======== deferred heads for step s-1 (wave 7, overlaps other waves' Phase G) ========
    if (w == 7 && s > 0){
      f32x4 hd = zz;
      #pragma unroll
      for (int kc=0;kc<4;++kc){
        bf16x8 ha = ldg8(&HN[l15*136 + kc*32 + lq*8]);
        bf16x8 hb = ldg8(Wh + (kc*64 + l)*8);
        hd = __builtin_amdgcn_mfma_f32_16x16x32_bf16(ha, hb, hd, 0,0,0);
      }
      if (lq == 0){
        #pragma unroll
        for (int r=0;r<NB;++r){
          const int b = b0 + r;
          const float v = hd[r] + bb;
          if (l15 < 6)       out_cmd[(b*S_ + (s-1))*6 + l15] = v;
          else if (l15 < 14) out_coord[(b*S_ + (s-1))*8 + (l15-6)] = v;
        }
      }
    }

    // ======== Phase G: gates (fp8 MFMA, all weights on-CU) + in-lane activations ========
    long afr[5];
    #pragma unroll
    for (int kc=0;kc<5;++kc)
      afr[kc] = *reinterpret_cast<const long*>(&A8[a_off + kc*32]);

    #pragma unroll
    for (int dtl=0; dtl<4; ++dtl){
      const int dt = w*4 + dtl;
      long bl[4];
      #pragma unroll
      for (int gt=0; gt<4; ++gt){
        const long t = Bwpl[(gt*32 + dt)*32 + (l & 31)];
        bl[gt] = (lq < 2) ? t : 0L;
      }
      f32x4 az[4] = {zz, zz, zz, zz};
      #pragma unroll
      for (int kc=0;kc<4;++kc)
        #pragma unroll
        for (int gt=0; gt<4; ++gt)
          az[gt] = __builtin_amdgcn_mfma_f32_16x16x32_fp8_fp8(afr[kc], bp[dtl][gt][kc], az[gt], 0,0,0);
      #pragma unroll
      for (int gt=0; gt<4; ++gt)
        az[gt] = __builtin_amdgcn_mfma_f32_16x16x32_fp8_fp8(afr[4], bl[gt], az[gt], 0,0,0);
      if (lq == 0){
        f32x4 cv[4];
        #pragma unroll
        for (int gt=0; gt<4; ++gt)
          cv[gt] = *reinterpret_cast<const f32x4*>(&ctx4[(gt*512 + dt*16 + l15)*NB]);
        #pragma unroll
        for (int r=0;r<NB;++r){
          const float iv = sigf  (az[0][r]*DSCALE + cv[0][r]);
          const float fv = sigf  (az[1][r]*DSCALE + cv[1][r]);
          const float gg = tanhft(az[2][r]*DSCALE + cv[2][r]);
          const float ov = sigf  (az[3][r]*DSCALE + cv[3][r]);
          const float cc = fv*c_st[dtl][r] + iv*gg;
          c_st[dtl][r] = cc;
          HF[r*520 + dt*16 + l15] = __float2bfloat16(ov*tanhft(cc));
        }
      }
    }
    __syncthreads();  // Bar1: HF ready

    // ======== Phase R: h = h_full · W_hr^T (A: HF clamp+mask; B: regs kc0-7, LDS kc8-15) ====
    f32x4 aA = zz, aB = zz;
    #pragma unroll
    for (int kk=0; kk<16; ++kk){
      uint4 av = *reinterpret_cast<const uint4*>(&HF[(l15 & 3)*520 + kk*32 + lq*8]);
      if (l15 >= 4){ av.x = 0u; av.y = 0u; av.z = 0u; av.w = 0u; }
      bf16x8 a2 = __builtin_bit_cast(bf16x8, av);
      bf16x8 b2;
      if (kk < 8) b2 = __builtin_bit_cast(bf16x8, wrr[kk]);
      else        b2 = ldg8(&Wr2L[((w*8 + (kk-8))*64 + l)*8]);
      if (kk & 1) aB = __builtin_amdgcn_mfma_f32_16x16x32_bf16(a2, b2, aB, 0,0,0);
      else        aA = __builtin_amdgcn_mfma_f32_16x16x32_bf16(a2, b2, aA, 0,0,0);
    }
    f32x4 acc2 = aA + aB;    // row (lq==0, r) = batch r, col p = w*16+l15

    // LN partials (butterfly over l15 bits)
    float sm[4], sq[4];
    #pragma unroll
    for (int r=0;r<NB;++r){
      float v = acc2[r];
      sm[r] = v; sq[r] = v*v;
      #pragma unroll
      for (int m=1;m<16;m<<=1){
        sm[r] += __shfl_xor(sm[r], m);
        sq[r] += __shfl_xor(sq[r], m);
      }
    }
    if (l == 0){
      f32x4 vm = {sm[0], sm[1], sm[2], sm[3]};
      f32x4 vq = {sq[0], sq[1], sq[2], sq[3]};
      *reinterpret_cast<f32x4*>(&s_m[w*4]) = vm;
      *reinterpret_cast<f32x4*>(&s_q[w*4]) = vq;
    }
    // x prefetch for step s+1 (A8 x-slot: safe between Bar1 and Bar2)
    if (s+1 < S_ && tid < 64){
      const int b = tid >> 4, c = tid & 15;
      A8[b*168 + 128 + c] = f2fp8(ASCALE * x_std[((b0+b)*S_ + s+1)*16 + c]);
    }
    __syncthreads();  // Bar2: s_m/s_q ready

    // ======== Phase E: mu/rs redundant, raw h -> A8, hn -> HN ========
    {
      f32x4 ms = zz, qs = zz;
      #pragma unroll
      for (int ww=0; ww<8; ++ww){
        ms += *reinterpret_cast<const f32x4*>(&s_m[ww*4]);
        qs += *reinterpret_cast<const f32x4*>(&s_q[ww*4]);
      }
      if (lq == 0){
        #pragma unroll
        for (int r=0;r<NB;++r){
          const float mu = ms[r] * (1.f/128.f);
          const float vr = qs[r] * (1.f/128.f) - mu*mu;
          const float rs = rsqrtf(vr + 1e-5f);
          const float h  = acc2[r];
          const float hn = (h - mu)*rs*lng + lnb;
          HN[r*136 + w*16 + l15] = __float2bfloat16(hn);
          A8[r*168 + w*16 + l15] = f2fp8(ASCALE * h);
        }
      }
    }
    __syncthreads();  // Bar3: A8/HN ready for next step
  }

  // ======== epilogue: heads for s = S_-1 (wave 7) ========
  if (w == 7){
    f32x4 hd = zz;
    #pragma unroll
    for (int kc=0;kc<4;++kc){
      bf16x8 ha = ldg8(&HN[l15*136 + kc*32 + lq*8]);
      bf16x8 hb = ldg8(Wh + (kc*64 + l)*8);
      hd = __builtin_amdgcn_mfma_f32_16x16x32_bf16(ha, hb, hd, 0,0,0);
    }
    if (lq == 0){
      #pragma unroll
      for (int r=0;r<NB;++r){
        const int b = b0 + r;
        const float v = hd[r] + bb;
        if (l15 < 6)       out_cmd[(b*S_ + (S_-1))*6 + l15] = v;
        else if (l15 < 14) out_coord[(b*S_ + (S_-1))*8 + (l15-6)] = v;
      }
    }
  }
}

extern "C" void kernel_launch(void* const* d_in, const int* in_sizes, int n_in,
                              void* d_out, int out_size, void* d_ws, size_t ws_size,
                              hipStream_t stream)
{
  const float* x_std       = (const float*)d_in[0];
  const float* context     = (const float*)d_in[1];
  const float* W_cmd       = (const float*)d_in[2];
  const float* b_cmd       = (const float*)d_in[3];
  const float* W_coord     = (const float*)d_in[4];
  const float* b_coord     = (const float*)d_in[5];
  const float* W_head      = (const float*)d_in[6];
  const float* b_head      = (const float*)d_in[7];
  const float* W_ih        = (const float*)d_in[8];
  const float* W_hh        = (const float*)d_in[9];
  const float* W_hr        = (const float*)d_in[10];
  const float* b_ih        = (const float*)d_in[11];
  const float* b_hh        = (const float*)d_in[12];
  const float* ln_g        = (const float*)d_in[13];
  const float* ln_b        = (const float*)d_in[14];
  const float* W_out_cmd   = (const float*)d_in[15];
  const float* b_out_cmd   = (const float*)d_in[16];
  const float* W_out_coord = (const float*)d_in[17];
  const float* b_out_coord = (const float*)d_in[18];

  float* out = (float*)d_out;
  char*  ws  = (char*)d_ws;

  unsigned char*  Bp   = (unsigned char*)(ws);              // 327680 B
  __hip_bfloat16* Wr2  = (__hip_bfloat16*)(ws + 327680);    // 131072 -> 458752
  __hip_bfloat16* Wh   = (__hip_bfloat16*)(ws + 458752);    // 4096   -> 462848
  float* btil          = (float*)(ws + 462848);             // 64     -> 462912
  float* b_fold        = (float*)(ws + 462912);             // 8192   -> 471104
  float* W_comb        = (float*)(ws + 471104);             // 131072 (dead after k_bp)
  float* ctxB          = (float*)(ws + 471104 + 131072);    // 2 MB -> ~2.6 MB total

  k_fold<<<dim3(G4), dim3(64), 0, stream>>>(W_ih, W_cmd, b_cmd, W_coord, b_coord,
                                            W_head, b_head, W_comb, b_fold);
  k_bp<<<dim3(1280), dim3(256), 0, stream>>>(W_hh, W_comb, Bp);
  k_wr2<<<dim3(256), dim3(256), 0, stream>>>(W_hr, Wr2);
  k_wout<<<dim3(9), dim3(256), 0, stream>>>(W_out_cmd, W_out_coord, b_out_cmd, b_out_coord,
                                            Wh, btil);
  k_ctx<<<dim3((B_*G4)/256), dim3(256), 0, stream>>>(context, W_ih, b_ih, b_hh,
                                                     b_fold, ctxB);
  k_scan<<<dim3(B_/NB), dim3(512), 0, stream>>>(x_std, ctxB, Bp, Wr2, Wh, btil, ln_g, ln_b,
                                                out, out + B_*S_*6);
}

// Round 9
// 1851.873 us; speedup vs baseline: 1.1662x; 1.1662x over previous
//
#include <hip/hip_runtime.h>
#include <hip/hip_bf16.h>
#include <stdint.h>

#define B_   256
#define S_   256
#define DM   512
#define G4   2048
#define LAT  128
#define PR   128
#define NB   4      // batches per block -> 64 blocks

typedef __bf16 bf16x8 __attribute__((ext_vector_type(8)));
typedef float  f32x4  __attribute__((ext_vector_type(4)));

__device__ __forceinline__ bf16x8 ldg8(const __hip_bfloat16* p){
  uint4 v = *reinterpret_cast<const uint4*>(p);
  return __builtin_bit_cast(bf16x8, v);
}
__device__ __forceinline__ float sigf(float x){ return 1.f/(1.f+__expf(-x)); }
__device__ __forceinline__ float tanhft(float x){ return 1.f - 2.f/(__expf(2.f*x)+1.f); }
__device__ __forceinline__ unsigned char f2fp8(float x){
  return (unsigned char)(__builtin_amdgcn_cvt_pk_fp8_f32(x, x, 0, false) & 0xff);
}

#define BSCALE 64.f
#define ASCALE 8.f
#define DSCALE (1.f/512.f)

// ================= prep 1: W_comb[2048][16] = W_ih[:, :512] · Wcat, + folded x-bias ===========
__global__ void k_fold(const float* __restrict__ W_ih,
                       const float* __restrict__ W_cmd, const float* __restrict__ b_cmd,
                       const float* __restrict__ W_coord, const float* __restrict__ b_coord,
                       const float* __restrict__ W_head, const float* __restrict__ b_head,
                       float* __restrict__ W_comb, float* __restrict__ b_fold)
{
  const int g = blockIdx.x;      // 2048
  const int lane = threadIdx.x;  // 64
  float p[17];
  #pragma unroll
  for (int k=0;k<17;++k) p[k]=0.f;
  for (int d = lane; d < DM; d += 64){
    float w = W_ih[g*640 + d];
    #pragma unroll
    for (int c=0;c<6;++c)  p[c]    += w * W_cmd[d*6+c];
    #pragma unroll
    for (int c=0;c<8;++c)  p[6+c]  += w * W_coord[d*8+c];
    p[14] += w * W_head[d*2+0];
    p[15] += w * W_head[d*2+1];
    p[16] += w * (b_cmd[d] + b_coord[d] + b_head[d]);
  }
  #pragma unroll
  for (int k=0;k<17;++k){
    #pragma unroll
    for (int off=32; off>0; off>>=1) p[k] += __shfl_xor(p[k], off);
  }
  if (lane == 0){
    #pragma unroll
    for (int k=0;k<16;++k) W_comb[g*16+k] = p[k];
    b_fold[g] = p[16];
  }
}

// ================= prep 2: gate-B fp8, scaled xBSCALE, fragment-linear ======================
__global__ void k_bp(const float* __restrict__ Whh, const float* __restrict__ W_comb,
                     unsigned char* __restrict__ Bp)
{
  const int flat = blockIdx.x*256 + threadIdx.x;   // 1280 blocks -> 327680
  const int j   = flat & 7;
  const int l   = (flat >> 3) & 63;
  const int idx = flat >> 9;                        // n*5 + kc
  const int n   = idx / 5;
  const int kc  = idx - n*5;
  const int g   = n*16 + (l & 15);
  const int k   = kc*32 + ((l >> 4) & 3)*8 + j;
  float v = (k < 128) ? Whh[g*PR + k] : ((k < 144) ? W_comb[g*16 + (k-128)] : 0.f);
  Bp[flat] = f2fp8(BSCALE * v);
}

// ================= prep 3: W_hr bf16 fragment-linear (8 tiles) ==============================
__global__ void k_wr2(const float* __restrict__ Whr, __hip_bfloat16* __restrict__ Wr2)
{
  const int flat = blockIdx.x*256 + threadIdx.x;   // 256 blocks: 8*16*64*8 = 65536
  const int j   = flat & 7;
  const int l   = (flat >> 3) & 63;
  const int kc  = (flat >> 9) & 15;
  const int tn  = flat >> 13;                       // 0..7
  const int row = tn*16 + (l & 15);                 // p < 128
  const int d   = kc*32 + ((l >> 4) & 3)*8 + j;
  Wr2[flat] = __float2bfloat16(Whr[row*DM + d]);
}

// ================= prep 4: Wh2[t][p] = ln_g[p]*Wo~[t][p] frag-linear; S12 = (S1|S2) =========
// Wo~ = cmd rows 0-5; coord rows 6-13 with cmd-dependence folded.
// head_t = rs*(P_t - mu*S1_t) + S2_t, P = rawh · Wh2^T
__global__ void k_wh2(const float* __restrict__ ln_g, const float* __restrict__ ln_b,
                      const float* __restrict__ Wocmd, const float* __restrict__ Wocoord,
                      const float* __restrict__ bocmd, const float* __restrict__ bocoord,
                      __hip_bfloat16* __restrict__ Wh2, float* __restrict__ S12)
{
  if (blockIdx.x == 8){
    const int t = threadIdx.x;
    if (t >= 14) return;
    float s1 = 0.f, s2 = 0.f;
    for (int p=0; p<PR; ++p){
      float wo;
      if (t < 6) wo = Wocmd[t*PR + p];
      else {
        wo = Wocoord[(t-6)*134 + p];
        for (int k=0;k<6;++k) wo += Wocoord[(t-6)*134 + 128 + k]*Wocmd[k*PR + p];
      }
      s1 += ln_g[p]*wo;
      s2 += ln_b[p]*wo;
    }
    if (t < 6) s2 += bocmd[t];
    else {
      s2 += bocoord[t-6];
      for (int k=0;k<6;++k) s2 += Wocoord[(t-6)*134 + 128 + k]*bocmd[k];
    }
    S12[t] = s1; S12[16+t] = s2;
    return;
  }
  const int flat = blockIdx.x*256 + threadIdx.x;   // 0..2047
  const int j  = flat & 7;
  const int l  = (flat >> 3) & 63;
  const int kc = flat >> 9;                         // 0..3
  const int t  = l & 15;
  const int p  = kc*32 + ((l >> 4) & 3)*8 + j;
  float v = 0.f;
  if (t < 6) v = Wocmd[t*PR + p];
  else if (t < 14){
    v = Wocoord[(t-6)*134 + p];
    for (int k=0;k<6;++k) v += Wocoord[(t-6)*134 + 128 + k]*Wocmd[k*PR + p];
  }
  Wh2[flat] = __float2bfloat16(ln_g[p] * v);
}

// ================= prep 5: ctxB[b][g] = b_ih+b_hh+b_fold + ctx[b]·W_ih[g,512:] (b-major) ====
__global__ void k_ctx(const float* __restrict__ context, const float* __restrict__ W_ih,
                      const float* __restrict__ b_ih, const float* __restrict__ b_hh,
                      const float* __restrict__ b_fold, float* __restrict__ ctxB)
{
  const int idx = blockIdx.x*256 + threadIdx.x;   // 2048 blocks * 256 = B_*G4
  const int b = idx >> 11;
  const int g = idx & 2047;
  float a = b_ih[g] + b_hh[g] + b_fold[g];
  const float4* cp = reinterpret_cast<const float4*>(context + b*LAT);
  const float4* wp = reinterpret_cast<const float4*>(W_ih + g*640 + DM);
  #pragma unroll 8
  for (int q=0; q<LAT/4; ++q){
    float4 c = cp[q], w = wp[q];
    a += c.x*w.x + c.y*w.y + c.z*w.z + c.w*w.w;
  }
  ctxB[idx] = a;   // [b][g]
}

// ================= fused MFMA LSTM scan: on-CU weights, distributed act, deferred LN ========
__global__ __launch_bounds__(512, 2)
void k_scan(const float* __restrict__ x_std,
            const float* __restrict__ ctxB,
            const unsigned char* __restrict__ Bp,
            const __hip_bfloat16* __restrict__ Wr2,
            const __hip_bfloat16* __restrict__ Wh2,
            const float* __restrict__ S12,
            float* __restrict__ out_cmd, float* __restrict__ out_coord)
{
  const int tid = threadIdx.x;
  const int w   = tid >> 6;        // wave 0..7
  const int l   = tid & 63;
  const int l15 = l & 15;
  const int lq  = l >> 4;          // 0..3
  const int b0  = blockIdx.x * NB;

  __shared__ __align__(16) __hip_bfloat16 Wr2L[8*6*64*8];   // 48 KB: Wr2 kc 10..15 per wave
  __shared__ __align__(8)  unsigned char  Bwp[128*32*8];    // 32 KB: kc4 packed (real half)
  __shared__ __align__(16) float Graw[G4*NB];               // 32 KB: raw gate sums [g][b]
  __shared__ __align__(16) __hip_bfloat16 HF[16*520];       // 16.6 KB [b][d], rows 4-15 zero
  __shared__ __align__(8)  unsigned char  A8[16*168];       // 2.7 KB [b][k] fp8, rows 4-15 zero
  __shared__ __align__(16) __hip_bfloat16 HN[16*136];       // 4.3 KB raw h bf16, rows 4-15 zero
  __shared__ float s_m[32], s_q[32];

  // ---- gate weights kc=0..3 -> 128 regs (expect AGPR) ----
  long bp[4][4][4];
  {
    const long* Bpl = reinterpret_cast<const long*>(Bp);
    #pragma unroll
    for (int dtl=0; dtl<4; ++dtl)
      #pragma unroll
      for (int gt=0; gt<4; ++gt)
        #pragma unroll
        for (int kc=0; kc<4; ++kc){
          const int n = gt*32 + w*4 + dtl;
          bp[dtl][gt][kc] = Bpl[(n*5 + kc)*64 + l];
        }
  }
  // ---- Wr2 kc 0..9 -> 40 VGPRs ----
  uint4 wrr[10];
  {
    const uint4* Wr2u4 = reinterpret_cast<const uint4*>(Wr2);
    #pragma unroll
    for (int kk=0; kk<10; ++kk)
      wrr[kk] = Wr2u4[(w*16 + kk)*64 + l];
  }
  // ---- stage Wr2 kc 10..15 -> LDS (3072 uint4) ----
  {
    const uint4* Wr2u4 = reinterpret_cast<const uint4*>(Wr2);
    uint4* dst = reinterpret_cast<uint4*>(Wr2L);
    for (int i = tid; i < 3072; i += 512){
      const int wi = i / 384;
      const int kk = (i - wi*384) >> 6;
      const int ll = i & 63;
      dst[i] = Wr2u4[(wi*16 + 10 + kk)*64 + ll];
    }
  }
  // ---- stage kc4 packed -> LDS (real half: orig lanes 0..31) ----
  {
    const long* Bpl = reinterpret_cast<const long*>(Bp);
    long* dst = reinterpret_cast<long*>(Bwp);
    for (int i = tid; i < 4096; i += 512)
      dst[i] = Bpl[((i>>5)*5 + 4)*64 + (i & 31)];
  }
  // ---- ctx -> 16 regs/thread (step-invariant; thread owns d = tid) ----
  float cx[4][4];
  #pragma unroll
  for (int gt=0; gt<4; ++gt)
    #pragma unroll
    for (int b=0; b<NB; ++b)
      cx[gt][b] = ctxB[(b0+b)*G4 + gt*512 + tid];

  // ---- S1/S2 for head lanes ----
  float S1k = 0.f, S2k = 0.f;
  if (l15 < 14){ S1k = S12[l15]; S2k = S12[16 + l15]; }

  // ---- zero LDS state (rows 4-15 stay zero forever) ----
  for (int i = tid; i < 16*520/2; i += 512) reinterpret_cast<unsigned*>(HF)[i] = 0u;
  for (int i = tid; i < 16*168/4; i += 512) reinterpret_cast<unsigned*>(A8)[i] = 0u;
  for (int i = tid; i < 16*136/2; i += 512) reinterpret_cast<unsigned*>(HN)[i] = 0u;
  __syncthreads();
  if (tid < 64){
    const int b = tid >> 4, c = tid & 15;
    A8[b*168 + 128 + c] = f2fp8(ASCALE * x_std[(b0+b)*S_*16 + c]);   // x at s=0
  }

  float c_st[NB] = {0.f, 0.f, 0.f, 0.f};   // cell state: thread owns dim d = tid
  __syncthreads();

  const f32x4 zz = {0.f, 0.f, 0.f, 0.f};
  const int a_off = l15*168 + lq*8;
  const long* Bwpl = reinterpret_cast<const long*>(Bwp);

  for (int s = 0; s < S_; ++s){
    // ======== deferred heads for step s-1 (wave 7; overlaps other waves' Phase G) ========
    if (w == 7 && s > 0){
      f32x4 ms = zz, qs = zz;
      #pragma unroll
      for (int ww=0; ww<8; ++ww){
        ms += *reinterpret_cast<const f32x4*>(&s_m[ww*4]);
        qs += *reinterpret_cast<const f32x4*>(&s_q[ww*4]);
      }
      f32x4 hd = zz;
      #pragma unroll
      for (int kc=0;kc<4;++kc){
        bf16x8 ha = ldg8(&HN[l15*136 + kc*32 + lq*8]);
        bf16x8 hb = ldg8(Wh2 + (kc*64 + l)*8);
        hd = __builtin_amdgcn_mfma_f32_16x16x32_bf16(ha, hb, hd, 0,0,0);
      }
      if (lq == 0){
        #pragma unroll
        for (int r=0;r<NB;++r){
          const float mu = ms[r] * (1.f/128.f);
          const float vr = qs[r] * (1.f/128.f) - mu*mu;
          const float rs = rsqrtf(vr + 1e-5f);
          const float v  = rs*(hd[r] - mu*S1k) + S2k;
          const int b = b0 + r;
          if (l15 < 6)       out_cmd[(b*S_ + (s-1))*6 + l15] = v;
          else if (l15 < 14) out_coord[(b*S_ + (s-1))*8 + (l15-6)] = v;
        }
      }
    }

    // ======== Phase G: raw gates = A8·B (fp8 MFMA, weights on-CU) -> Graw ========
    long afr[5];
    #pragma unroll
    for (int kc=0;kc<5;++kc)
      afr[kc] = *reinterpret_cast<const long*>(&A8[a_off + kc*32]);

    #pragma unroll
    for (int dtl=0; dtl<4; ++dtl){
      const int dt = w*4 + dtl;
      long bl[4];
      #pragma unroll
      for (int gt=0; gt<4; ++gt){
        const long t0 = Bwpl[(gt*32 + dt)*32 + (l & 31)];
        bl[gt] = (lq < 2) ? t0 : 0L;
      }
      f32x4 az[4] = {zz, zz, zz, zz};
      #pragma unroll
      for (int kc=0;kc<4;++kc)
        #pragma unroll
        for (int gt=0; gt<4; ++gt)
          az[gt] = __builtin_amdgcn_mfma_f32_16x16x32_fp8_fp8(afr[kc], bp[dtl][gt][kc], az[gt], 0,0,0);
      #pragma unroll
      for (int gt=0; gt<4; ++gt)
        az[gt] = __builtin_amdgcn_mfma_f32_16x16x32_fp8_fp8(afr[4], bl[gt], az[gt], 0,0,0);
      if (lq == 0){
        #pragma unroll
        for (int gt=0; gt<4; ++gt)
          *reinterpret_cast<f32x4*>(&Graw[(gt*512 + dt*16 + l15)*NB]) = az[gt];
      }
    }
    __syncthreads();  // Bar1: Graw ready (A8 x-slot reads also done)

    // ======== Phase A: activations distributed (thread owns d = tid, 4 batches) ========
    {
      const int d = tid;
      f32x4 gv[4];
      #pragma unroll
      for (int gt=0; gt<4; ++gt)
        gv[gt] = *reinterpret_cast<const f32x4*>(&Graw[(gt*512 + d)*NB]);
      #pragma unroll
      for (int b=0; b<NB; ++b){
        const float iv = sigf  (gv[0][b]*DSCALE + cx[0][b]);
        const float fv = sigf  (gv[1][b]*DSCALE + cx[1][b]);
        const float gg = tanhft(gv[2][b]*DSCALE + cx[2][b]);
        const float ov = sigf  (gv[3][b]*DSCALE + cx[3][b]);
        const float cc = fv*c_st[b] + iv*gg;
        c_st[b] = cc;
        HF[b*520 + d] = __float2bfloat16(ov*tanhft(cc));
      }
    }
    // x prefetch for step s+1 (A8 x-slot read was pre-Bar1)
    if (s+1 < S_ && tid < 64){
      const int b = tid >> 4, c = tid & 15;
      A8[b*168 + 128 + c] = f2fp8(ASCALE * x_std[((b0+b)*S_ + s+1)*16 + c]);
    }
    __syncthreads();  // Bar2: HF ready

    // ======== Phase R: h = h_full · W_hr^T (B: 10 frags regs + 6 LDS; zero-padded A) ========
    f32x4 aA = zz, aB = zz;
    #pragma unroll
    for (int kk=0; kk<16; ++kk){
      bf16x8 a2 = ldg8(&HF[l15*520 + kk*32 + lq*8]);
      bf16x8 b2;
      if (kk < 10) b2 = __builtin_bit_cast(bf16x8, wrr[kk]);
      else         b2 = ldg8(&Wr2L[((w*6 + (kk-10))*64 + l)*8]);
      if (kk & 1) aB = __builtin_amdgcn_mfma_f32_16x16x32_bf16(a2, b2, aB, 0,0,0);
      else        aA = __builtin_amdgcn_mfma_f32_16x16x32_bf16(a2, b2, aA, 0,0,0);
    }
    f32x4 acc2 = aA + aB;    // row (lq==0, r) = batch r, col p = w*16+l15

    // LN partial sums (butterfly over l15 bits)
    float sm[4], sq[4];
    #pragma unroll
    for (int r=0;r<NB;++r){
      float v = acc2[r];
      sm[r] = v; sq[r] = v*v;
      #pragma unroll
      for (int m=1;m<16;m<<=1){
        sm[r] += __shfl_xor(sm[r], m);
        sq[r] += __shfl_xor(sq[r], m);
      }
    }
    if (l == 0){
      f32x4 vm = {sm[0], sm[1], sm[2], sm[3]};
      f32x4 vq = {sq[0], sq[1], sq[2], sq[3]};
      *reinterpret_cast<f32x4*>(&s_m[w*4]) = vm;
      *reinterpret_cast<f32x4*>(&s_q[w*4]) = vq;
    }
    // raw h -> A8 (fp8 recurrent state) and HN (bf16 for deferred heads)
    if (lq == 0){
      #pragma unroll
      for (int r=0;r<NB;++r){
        const float h = acc2[r];
        HN[r*136 + w*16 + l15] = __float2bfloat16(h);
        A8[r*168 + w*16 + l15] = f2fp8(ASCALE * h);
      }
    }
    __syncthreads();  // Bar3: A8/HN/s_mq ready for next step
  }

  // ======== epilogue: heads for s = S_-1 (wave 7) ========
  if (w == 7){
    f32x4 ms = zz, qs = zz;
    #pragma unroll
    for (int ww=0; ww<8; ++ww){
      ms += *reinterpret_cast<const f32x4*>(&s_m[ww*4]);
      qs += *reinterpret_cast<const f32x4*>(&s_q[ww*4]);
    }
    f32x4 hd = zz;
    #pragma unroll
    for (int kc=0;kc<4;++kc){
      bf16x8 ha = ldg8(&HN[l15*136 + kc*32 + lq*8]);
      bf16x8 hb = ldg8(Wh2 + (kc*64 + l)*8);
      hd = __builtin_amdgcn_mfma_f32_16x16x32_bf16(ha, hb, hd, 0,0,0);
    }
    if (lq == 0){
      #pragma unroll
      for (int r=0;r<NB;++r){
        const float mu = ms[r] * (1.f/128.f);
        const float vr = qs[r] * (1.f/128.f) - mu*mu;
        const float rs = rsqrtf(vr + 1e-5f);
        const float v  = rs*(hd[r] - mu*S1k) + S2k;
        const int b = b0 + r;
        if (l15 < 6)       out_cmd[(b*S_ + (S_-1))*6 + l15] = v;
        else if (l15 < 14) out_coord[(b*S_ + (S_-1))*8 + (l15-6)] = v;
      }
    }
  }
}

extern "C" void kernel_launch(void* const* d_in, const int* in_sizes, int n_in,
                              void* d_out, int out_size, void* d_ws, size_t ws_size,
                              hipStream_t stream)
{
  const float* x_std       = (const float*)d_in[0];
  const float* context     = (const float*)d_in[1];
  const float* W_cmd       = (const float*)d_in[2];
  const float* b_cmd       = (const float*)d_in[3];
  const float* W_coord     = (const float*)d_in[4];
  const float* b_coord     = (const float*)d_in[5];
  const float* W_head      = (const float*)d_in[6];
  const float* b_head      = (const float*)d_in[7];
  const float* W_ih        = (const float*)d_in[8];
  const float* W_hh        = (const float*)d_in[9];
  const float* W_hr        = (const float*)d_in[10];
  const float* b_ih        = (const float*)d_in[11];
  const float* b_hh        = (const float*)d_in[12];
  const float* ln_g        = (const float*)d_in[13];
  const float* ln_b        = (const float*)d_in[14];
  const float* W_out_cmd   = (const float*)d_in[15];
  const float* b_out_cmd   = (const float*)d_in[16];
  const float* W_out_coord = (const float*)d_in[17];
  const float* b_out_coord = (const float*)d_in[18];

  float* out = (float*)d_out;
  char*  ws  = (char*)d_ws;

  unsigned char*  Bp   = (unsigned char*)(ws);              // 327680
  __hip_bfloat16* Wr2  = (__hip_bfloat16*)(ws + 327680);    // 131072 -> 458752
  __hip_bfloat16* Wh2  = (__hip_bfloat16*)(ws + 458752);    // 4096   -> 462848
  float* S12           = (float*)(ws + 462848);             // 128    -> 462976
  float* b_fold        = (float*)(ws + 462976);             // 8192   -> 471168
  float* W_comb        = (float*)(ws + 471168);             // 131072 -> 602240 (dead after k_bp)
  float* ctxB          = (float*)(ws + 602240);             // 2097152 -> 2699392 total

  k_fold<<<dim3(G4), dim3(64), 0, stream>>>(W_ih, W_cmd, b_cmd, W_coord, b_coord,
                                            W_head, b_head, W_comb, b_fold);
  k_bp<<<dim3(1280), dim3(256), 0, stream>>>(W_hh, W_comb, Bp);
  k_wr2<<<dim3(256), dim3(256), 0, stream>>>(W_hr, Wr2);
  k_wh2<<<dim3(9), dim3(256), 0, stream>>>(ln_g, ln_b, W_out_cmd, W_out_coord,
                                           b_out_cmd, b_out_coord, Wh2, S12);
  k_ctx<<<dim3((B_*G4)/256), dim3(256), 0, stream>>>(context, W_ih, b_ih, b_hh,
                                                     b_fold, ctxB);
  k_scan<<<dim3(B_/NB), dim3(512), 0, stream>>>(x_std, ctxB, Bp, Wr2, Wh2, S12,
                                                out, out + B_*S_*6);
}

// Round 10
// 1109.531 us; speedup vs baseline: 1.9465x; 1.6691x over previous
//
#include <hip/hip_runtime.h>
#include <hip/hip_bf16.h>
#include <stdint.h>

#define B_   256
#define S_   256
#define DM   512
#define G4   2048
#define LAT  128
#define PR   128
#define NB   4      // batches per block -> 64 blocks

typedef __bf16 bf16x8 __attribute__((ext_vector_type(8)));
typedef float  f32x4  __attribute__((ext_vector_type(4)));

__device__ __forceinline__ bf16x8 ldg8(const __hip_bfloat16* p){
  uint4 v = *reinterpret_cast<const uint4*>(p);
  return __builtin_bit_cast(bf16x8, v);
}
__device__ __forceinline__ float sigf(float x){ return 1.f/(1.f+__expf(-x)); }
__device__ __forceinline__ float tanhft(float x){ return 1.f - 2.f/(__expf(2.f*x)+1.f); }
__device__ __forceinline__ unsigned char f2fp8(float x){
  return (unsigned char)(__builtin_amdgcn_cvt_pk_fp8_f32(x, x, 0, false) & 0xff);
}

#define BSCALE 64.f
#define ASCALE 8.f
#define DSCALE (1.f/512.f)

// ================= prep 1: W_comb[2048][16] = W_ih[:, :512] · Wcat, + folded x-bias ===========
__global__ void k_fold(const float* __restrict__ W_ih,
                       const float* __restrict__ W_cmd, const float* __restrict__ b_cmd,
                       const float* __restrict__ W_coord, const float* __restrict__ b_coord,
                       const float* __restrict__ W_head, const float* __restrict__ b_head,
                       float* __restrict__ W_comb, float* __restrict__ b_fold)
{
  const int g = blockIdx.x;      // 2048
  const int lane = threadIdx.x;  // 64
  float p[17];
  #pragma unroll
  for (int k=0;k<17;++k) p[k]=0.f;
  for (int d = lane; d < DM; d += 64){
    float w = W_ih[g*640 + d];
    #pragma unroll
    for (int c=0;c<6;++c)  p[c]    += w * W_cmd[d*6+c];
    #pragma unroll
    for (int c=0;c<8;++c)  p[6+c]  += w * W_coord[d*8+c];
    p[14] += w * W_head[d*2+0];
    p[15] += w * W_head[d*2+1];
    p[16] += w * (b_cmd[d] + b_coord[d] + b_head[d]);
  }
  #pragma unroll
  for (int k=0;k<17;++k){
    #pragma unroll
    for (int off=32; off>0; off>>=1) p[k] += __shfl_xor(p[k], off);
  }
  if (lane == 0){
    #pragma unroll
    for (int k=0;k<16;++k) W_comb[g*16+k] = p[k];
    b_fold[g] = p[16];
  }
}

// ================= prep 2: gate-B fp8, scaled xBSCALE, fragment-linear ======================
__global__ void k_bp(const float* __restrict__ Whh, const float* __restrict__ W_comb,
                     unsigned char* __restrict__ Bp)
{
  const int flat = blockIdx.x*256 + threadIdx.x;   // 1280 blocks -> 327680
  const int j   = flat & 7;
  const int l   = (flat >> 3) & 63;
  const int idx = flat >> 9;                        // n*5 + kc
  const int n   = idx / 5;
  const int kc  = idx - n*5;
  const int g   = n*16 + (l & 15);
  const int k   = kc*32 + ((l >> 4) & 3)*8 + j;
  float v = (k < 128) ? Whh[g*PR + k] : ((k < 144) ? W_comb[g*16 + (k-128)] : 0.f);
  Bp[flat] = f2fp8(BSCALE * v);
}

// ================= prep 3: W_hr bf16 fragment-linear (8 tiles) ==============================
__global__ void k_wr2(const float* __restrict__ Whr, __hip_bfloat16* __restrict__ Wr2)
{
  const int flat = blockIdx.x*256 + threadIdx.x;   // 256 blocks: 8*16*64*8 = 65536
  const int j   = flat & 7;
  const int l   = (flat >> 3) & 63;
  const int kc  = (flat >> 9) & 15;
  const int tn  = flat >> 13;                       // 0..7
  const int row = tn*16 + (l & 15);                 // p < 128
  const int d   = kc*32 + ((l >> 4) & 3)*8 + j;
  Wr2[flat] = __float2bfloat16(Whr[row*DM + d]);
}

// ================= prep 4: Wh2[t][p] frag-linear: t<14 = ln_g*Wo~; t==14 = 1 (Σh col) ======
// head_t = rs*(P_t - mu*S1_t) + S2_t, P = rawh · Wh2^T ; mu from P_14 = Σh
__global__ void k_wh2(const float* __restrict__ ln_g, const float* __restrict__ ln_b,
                      const float* __restrict__ Wocmd, const float* __restrict__ Wocoord,
                      const float* __restrict__ bocmd, const float* __restrict__ bocoord,
                      __hip_bfloat16* __restrict__ Wh2, float* __restrict__ S12)
{
  if (blockIdx.x == 8){
    const int t = threadIdx.x;
    if (t >= 14) return;
    float s1 = 0.f, s2 = 0.f;
    for (int p=0; p<PR; ++p){
      float wo;
      if (t < 6) wo = Wocmd[t*PR + p];
      else {
        wo = Wocoord[(t-6)*134 + p];
        for (int k=0;k<6;++k) wo += Wocoord[(t-6)*134 + 128 + k]*Wocmd[k*PR + p];
      }
      s1 += ln_g[p]*wo;
      s2 += ln_b[p]*wo;
    }
    if (t < 6) s2 += bocmd[t];
    else {
      s2 += bocoord[t-6];
      for (int k=0;k<6;++k) s2 += Wocoord[(t-6)*134 + 128 + k]*bocmd[k];
    }
    S12[t] = s1; S12[16+t] = s2;
    return;
  }
  const int flat = blockIdx.x*256 + threadIdx.x;   // 0..2047
  const int j  = flat & 7;
  const int l  = (flat >> 3) & 63;
  const int kc = flat >> 9;                         // 0..3
  const int t  = l & 15;
  const int p  = kc*32 + ((l >> 4) & 3)*8 + j;
  float v = 0.f;
  if (t < 6) v = Wocmd[t*PR + p];
  else if (t < 14){
    v = Wocoord[(t-6)*134 + p];
    for (int k=0;k<6;++k) v += Wocoord[(t-6)*134 + 128 + k]*Wocmd[k*PR + p];
  }
  else if (t == 14) v = 1.0f;                       // Σh column (raw, unscaled)
  Wh2[flat] = __float2bfloat16(t == 14 ? v : ln_g[p] * v);
}

// ================= prep 5: ctxB[b][g] = b_ih+b_hh+b_fold + ctx[b]·W_ih[g,512:] (b-major) ====
__global__ void k_ctx(const float* __restrict__ context, const float* __restrict__ W_ih,
                      const float* __restrict__ b_ih, const float* __restrict__ b_hh,
                      const float* __restrict__ b_fold, float* __restrict__ ctxB)
{
  const int idx = blockIdx.x*256 + threadIdx.x;   // 2048 blocks * 256 = B_*G4
  const int b = idx >> 11;
  const int g = idx & 2047;
  float a = b_ih[g] + b_hh[g] + b_fold[g];
  const float4* cp = reinterpret_cast<const float4*>(context + b*LAT);
  const float4* wp = reinterpret_cast<const float4*>(W_ih + g*640 + DM);
  #pragma unroll 8
  for (int q=0; q<LAT/4; ++q){
    float4 c = cp[q], w = wp[q];
    a += c.x*w.x + c.y*w.y + c.z*w.z + c.w*w.w;
  }
  ctxB[idx] = a;   // [b][g]
}

// ================= fused MFMA LSTM scan: MFMA-based LN moments, no butterflies ==============
__global__ __launch_bounds__(512, 2)
void k_scan(const float* __restrict__ x_std,
            const float* __restrict__ ctxB,
            const unsigned char* __restrict__ Bp,
            const __hip_bfloat16* __restrict__ Wr2,
            const __hip_bfloat16* __restrict__ Wh2,
            const float* __restrict__ S12,
            float* __restrict__ out_cmd, float* __restrict__ out_coord)
{
  const int tid = threadIdx.x;
  const int w   = tid >> 6;        // wave 0..7
  const int l   = tid & 63;
  const int l15 = l & 15;
  const int lq  = l >> 4;          // 0..3
  const int b0  = blockIdx.x * NB;

  __shared__ __align__(16) __hip_bfloat16 Wr2L[8*6*64*8];   // 48 KB: Wr2 kc 10..15 per wave
  __shared__ __align__(8)  unsigned char  Bwp[128*32*8];    // 32 KB: kc4 packed (real half)
  __shared__ __align__(16) float Graw[G4*NB];               // 32 KB: raw gate sums [g][b]
  __shared__ __align__(16) __hip_bfloat16 HF[16*520];       // 16.6 KB [b][d], rows 4-15 zero
  __shared__ __align__(16) __hip_bfloat16 Wh2L[4*64*8];     // 4 KB: head B-frags
  __shared__ __align__(8)  unsigned char  A8[16*168];       // 2.7 KB [b][k] fp8, rows 4-15 zero
  __shared__ __align__(16) __hip_bfloat16 HN[16*136];       // 4.3 KB raw h bf16, rows 4-15 zero

  // ---- gate weights kc=0..3 -> 128 regs (AGPR) ----
  long bp[4][4][4];
  {
    const long* Bpl = reinterpret_cast<const long*>(Bp);
    #pragma unroll
    for (int dtl=0; dtl<4; ++dtl)
      #pragma unroll
      for (int gt=0; gt<4; ++gt)
        #pragma unroll
        for (int kc=0; kc<4; ++kc){
          const int n = gt*32 + w*4 + dtl;
          bp[dtl][gt][kc] = Bpl[(n*5 + kc)*64 + l];
        }
  }
  // ---- Wr2 kc 0..9 -> 40 VGPRs ----
  uint4 wrr[10];
  {
    const uint4* Wr2u4 = reinterpret_cast<const uint4*>(Wr2);
    #pragma unroll
    for (int kk=0; kk<10; ++kk)
      wrr[kk] = Wr2u4[(w*16 + kk)*64 + l];
  }
  // ---- stage Wr2 kc 10..15 -> LDS (3072 uint4) ----
  {
    const uint4* Wr2u4 = reinterpret_cast<const uint4*>(Wr2);
    uint4* dst = reinterpret_cast<uint4*>(Wr2L);
    for (int i = tid; i < 3072; i += 512){
      const int wi = i / 384;
      const int kk = (i - wi*384) >> 6;
      const int ll = i & 63;
      dst[i] = Wr2u4[(wi*16 + 10 + kk)*64 + ll];
    }
  }
  // ---- stage kc4 packed -> LDS (real half: orig lanes 0..31) ----
  {
    const long* Bpl = reinterpret_cast<const long*>(Bp);
    long* dst = reinterpret_cast<long*>(Bwp);
    for (int i = tid; i < 4096; i += 512)
      dst[i] = Bpl[((i>>5)*5 + 4)*64 + (i & 31)];
  }
  // ---- stage Wh2 -> LDS (256 uint4) ----
  {
    const uint4* src = reinterpret_cast<const uint4*>(Wh2);
    uint4* dst = reinterpret_cast<uint4*>(Wh2L);
    for (int i = tid; i < 256; i += 512) dst[i] = src[i];
  }
  // ---- ctx -> 16 regs/thread (step-invariant; thread owns d = tid) ----
  float cx[4][4];
  #pragma unroll
  for (int gt=0; gt<4; ++gt)
    #pragma unroll
    for (int b=0; b<NB; ++b)
      cx[gt][b] = ctxB[(b0+b)*G4 + gt*512 + tid];

  // ---- S1/S2 for head lanes ----
  float S1k = 0.f, S2k = 0.f;
  if (l15 < 14){ S1k = S12[l15]; S2k = S12[16 + l15]; }

  // ---- zero LDS state (rows 4-15 stay zero forever) ----
  for (int i = tid; i < 16*520/2; i += 512) reinterpret_cast<unsigned*>(HF)[i] = 0u;
  for (int i = tid; i < 16*168/4; i += 512) reinterpret_cast<unsigned*>(A8)[i] = 0u;
  for (int i = tid; i < 16*136/2; i += 512) reinterpret_cast<unsigned*>(HN)[i] = 0u;
  __syncthreads();
  if (tid < 64){
    const int b = tid >> 4, c = tid & 15;
    A8[b*168 + 128 + c] = f2fp8(ASCALE * x_std[(b0+b)*S_*16 + c]);   // x at s=0
  }

  float c_st[NB] = {0.f, 0.f, 0.f, 0.f};   // cell state: thread owns dim d = tid
  __syncthreads();

  const f32x4 zz = {0.f, 0.f, 0.f, 0.f};
  const int a_off = l15*168 + lq*8;
  const long* Bwpl = reinterpret_cast<const long*>(Bwp);

  for (int s = 0; s < S_; ++s){
    // ==== deferred heads + LN moments for step s-1 (wave 7; overlaps other waves' G) ====
    if (w == 7 && s > 0){
      __builtin_amdgcn_s_setprio(1);
      f32x4 hd = zz, ss = zz;
      #pragma unroll
      for (int kc=0;kc<4;++kc){
        bf16x8 ha = ldg8(&HN[l15*136 + kc*32 + lq*8]);
        bf16x8 hb = ldg8(&Wh2L[(kc*64 + l)*8]);
        hd = __builtin_amdgcn_mfma_f32_16x16x32_bf16(ha, hb, hd, 0,0,0);
        ss = __builtin_amdgcn_mfma_f32_16x16x32_bf16(ha, ha, ss, 0,0,0);
      }
      // mu from Σh column (col 14), Σh² from self-MFMA diagonal
      float mu[NB], rs[NB];
      #pragma unroll
      for (int r=0;r<NB;++r){
        const float sh = __shfl(hd[r], 14);          // lane (lq=0,l15=14), reg r
        const float s2 = __shfl(ss[r], r);           // lane (lq=0,l15=r),  reg r
        const float m  = sh * (1.f/128.f);
        const float vr = s2 * (1.f/128.f) - m*m;
        mu[r] = m; rs[r] = rsqrtf(vr + 1e-5f);
      }
      if (lq == 0){
        #pragma unroll
        for (int r=0;r<NB;++r){
          const float v = rs[r]*(hd[r] - mu[r]*S1k) + S2k;
          const int b = b0 + r;
          if (l15 < 6)       out_cmd[(b*S_ + (s-1))*6 + l15] = v;
          else if (l15 < 14) out_coord[(b*S_ + (s-1))*8 + (l15-6)] = v;
        }
      }
      __builtin_amdgcn_s_setprio(0);
    }

    // ======== Phase G: raw gates = A8·B (fp8 MFMA, weights on-CU) -> Graw ========
    long afr[5];
    #pragma unroll
    for (int kc=0;kc<5;++kc)
      afr[kc] = *reinterpret_cast<const long*>(&A8[a_off + kc*32]);

    #pragma unroll
    for (int dtl=0; dtl<4; ++dtl){
      const int dt = w*4 + dtl;
      long bl[4];
      #pragma unroll
      for (int gt=0; gt<4; ++gt){
        const long t0 = Bwpl[(gt*32 + dt)*32 + (l & 31)];
        bl[gt] = (lq < 2) ? t0 : 0L;
      }
      f32x4 az[4] = {zz, zz, zz, zz};
      #pragma unroll
      for (int kc=0;kc<4;++kc)
        #pragma unroll
        for (int gt=0; gt<4; ++gt)
          az[gt] = __builtin_amdgcn_mfma_f32_16x16x32_fp8_fp8(afr[kc], bp[dtl][gt][kc], az[gt], 0,0,0);
      #pragma unroll
      for (int gt=0; gt<4; ++gt)
        az[gt] = __builtin_amdgcn_mfma_f32_16x16x32_fp8_fp8(afr[4], bl[gt], az[gt], 0,0,0);
      if (lq == 0){
        #pragma unroll
        for (int gt=0; gt<4; ++gt)
          *reinterpret_cast<f32x4*>(&Graw[(gt*512 + dt*16 + l15)*NB]) = az[gt];
      }
    }
    __syncthreads();  // Bar1: Graw ready (A8 x-slot reads also done)

    // ======== Phase A: activations distributed (thread owns d = tid, 4 batches) ========
    {
      const int d = tid;
      f32x4 gv[4];
      #pragma unroll
      for (int gt=0; gt<4; ++gt)
        gv[gt] = *reinterpret_cast<const f32x4*>(&Graw[(gt*512 + d)*NB]);
      #pragma unroll
      for (int b=0; b<NB; ++b){
        const float iv = sigf  (gv[0][b]*DSCALE + cx[0][b]);
        const float fv = sigf  (gv[1][b]*DSCALE + cx[1][b]);
        const float gg = tanhft(gv[2][b]*DSCALE + cx[2][b]);
        const float ov = sigf  (gv[3][b]*DSCALE + cx[3][b]);
        const float cc = fv*c_st[b] + iv*gg;
        c_st[b] = cc;
        HF[b*520 + d] = __float2bfloat16(ov*tanhft(cc));
      }
    }
    // x prefetch for step s+1 (A8 x-slot read was pre-Bar1)
    if (s+1 < S_ && tid < 64){
      const int b = tid >> 4, c = tid & 15;
      A8[b*168 + 128 + c] = f2fp8(ASCALE * x_std[((b0+b)*S_ + s+1)*16 + c]);
    }
    __syncthreads();  // Bar2: HF ready

    // ======== Phase R: h = h_full · W_hr^T (B: 10 frags regs + 6 LDS; zero-padded A) ========
    f32x4 aA = zz, aB = zz;
    #pragma unroll
    for (int kk=0; kk<16; ++kk){
      bf16x8 a2 = ldg8(&HF[l15*520 + kk*32 + lq*8]);
      bf16x8 b2;
      if (kk < 10) b2 = __builtin_bit_cast(bf16x8, wrr[kk]);
      else         b2 = ldg8(&Wr2L[((w*6 + (kk-10))*64 + l)*8]);
      if (kk & 1) aB = __builtin_amdgcn_mfma_f32_16x16x32_bf16(a2, b2, aB, 0,0,0);
      else        aA = __builtin_amdgcn_mfma_f32_16x16x32_bf16(a2, b2, aA, 0,0,0);
    }
    f32x4 acc2 = aA + aB;    // row (lq==0, r) = batch r, col p = w*16+l15

    // raw h -> A8 (fp8 recurrent state) and HN (bf16 for deferred heads/LN moments)
    if (lq == 0){
      #pragma unroll
      for (int r=0;r<NB;++r){
        const float h = acc2[r];
        HN[r*136 + w*16 + l15] = __float2bfloat16(h);
        A8[r*168 + w*16 + l15] = f2fp8(ASCALE * h);
      }
    }
    __syncthreads();  // Bar3: A8/HN ready for next step
  }

  // ======== epilogue: heads for s = S_-1 (wave 7) ========
  if (w == 7){
    f32x4 hd = zz, ss = zz;
    #pragma unroll
    for (int kc=0;kc<4;++kc){
      bf16x8 ha = ldg8(&HN[l15*136 + kc*32 + lq*8]);
      bf16x8 hb = ldg8(&Wh2L[(kc*64 + l)*8]);
      hd = __builtin_amdgcn_mfma_f32_16x16x32_bf16(ha, hb, hd, 0,0,0);
      ss = __builtin_amdgcn_mfma_f32_16x16x32_bf16(ha, ha, ss, 0,0,0);
    }
    float mu[NB], rs[NB];
    #pragma unroll
    for (int r=0;r<NB;++r){
      const float sh = __shfl(hd[r], 14);
      const float s2 = __shfl(ss[r], r);
      const float m  = sh * (1.f/128.f);
      const float vr = s2 * (1.f/128.f) - m*m;
      mu[r] = m; rs[r] = rsqrtf(vr + 1e-5f);
    }
    if (lq == 0){
      #pragma unroll
      for (int r=0;r<NB;++r){
        const float v = rs[r]*(hd[r] - mu[r]*S1k) + S2k;
        const int b = b0 + r;
        if (l15 < 6)       out_cmd[(b*S_ + (S_-1))*6 + l15] = v;
        else if (l15 < 14) out_coord[(b*S_ + (S_-1))*8 + (l15-6)] = v;
      }
    }
  }
}

extern "C" void kernel_launch(void* const* d_in, const int* in_sizes, int n_in,
                              void* d_out, int out_size, void* d_ws, size_t ws_size,
                              hipStream_t stream)
{
  const float* x_std       = (const float*)d_in[0];
  const float* context     = (const float*)d_in[1];
  const float* W_cmd       = (const float*)d_in[2];
  const float* b_cmd       = (const float*)d_in[3];
  const float* W_coord     = (const float*)d_in[4];
  const float* b_coord     = (const float*)d_in[5];
  const float* W_head      = (const float*)d_in[6];
  const float* b_head      = (const float*)d_in[7];
  const float* W_ih        = (const float*)d_in[8];
  const float* W_hh        = (const float*)d_in[9];
  const float* W_hr        = (const float*)d_in[10];
  const float* b_ih        = (const float*)d_in[11];
  const float* b_hh        = (const float*)d_in[12];
  const float* ln_g        = (const float*)d_in[13];
  const float* ln_b        = (const float*)d_in[14];
  const float* W_out_cmd   = (const float*)d_in[15];
  const float* b_out_cmd   = (const float*)d_in[16];
  const float* W_out_coord = (const float*)d_in[17];
  const float* b_out_coord = (const float*)d_in[18];

  float* out = (float*)d_out;
  char*  ws  = (char*)d_ws;

  unsigned char*  Bp   = (unsigned char*)(ws);              // 327680
  __hip_bfloat16* Wr2  = (__hip_bfloat16*)(ws + 327680);    // 131072 -> 458752
  __hip_bfloat16* Wh2  = (__hip_bfloat16*)(ws + 458752);    // 4096   -> 462848
  float* S12           = (float*)(ws + 462848);             // 128    -> 462976
  float* b_fold        = (float*)(ws + 462976);             // 8192   -> 471168
  float* W_comb        = (float*)(ws + 471168);             // 131072 -> 602240 (dead after k_bp)
  float* ctxB          = (float*)(ws + 602240);             // 2097152 -> 2699392 total

  k_fold<<<dim3(G4), dim3(64), 0, stream>>>(W_ih, W_cmd, b_cmd, W_coord, b_coord,
                                            W_head, b_head, W_comb, b_fold);
  k_bp<<<dim3(1280), dim3(256), 0, stream>>>(W_hh, W_comb, Bp);
  k_wr2<<<dim3(256), dim3(256), 0, stream>>>(W_hr, Wr2);
  k_wh2<<<dim3(9), dim3(256), 0, stream>>>(ln_g, ln_b, W_out_cmd, W_out_coord,
                                           b_out_cmd, b_out_coord, Wh2, S12);
  k_ctx<<<dim3((B_*G4)/256), dim3(256), 0, stream>>>(context, W_ih, b_ih, b_hh,
                                                     b_fold, ctxB);
  k_scan<<<dim3(B_/NB), dim3(512), 0, stream>>>(x_std, ctxB, Bp, Wr2, Wh2, S12,
                                                out, out + B_*S_*6);
}

// Round 11
// 986.768 us; speedup vs baseline: 2.1887x; 1.1244x over previous
//
#include <hip/hip_runtime.h>
#include <hip/hip_bf16.h>
#include <stdint.h>

#define B_   256
#define S_   256
#define DM   512
#define G4   2048
#define LAT  128
#define PR   128
#define NB   4      // batches per block -> 64 blocks

typedef __bf16 bf16x8 __attribute__((ext_vector_type(8)));
typedef float  f32x4  __attribute__((ext_vector_type(4)));

__device__ __forceinline__ bf16x8 ldg8(const __hip_bfloat16* p){
  uint4 v = *reinterpret_cast<const uint4*>(p);
  return __builtin_bit_cast(bf16x8, v);
}
__device__ __forceinline__ float sigf(float x){ return 1.f/(1.f+__expf(-x)); }
__device__ __forceinline__ float tanhft(float x){ return 1.f - 2.f/(__expf(2.f*x)+1.f); }
__device__ __forceinline__ unsigned char f2fp8(float x){
  return (unsigned char)(__builtin_amdgcn_cvt_pk_fp8_f32(x, x, 0, false) & 0xff);
}

#define BSCALE 64.f
#define ASCALE 8.f
#define DSCALE (1.f/512.f)

// lgkm-only barrier: LDS producers drained, s_barrier, NO vmcnt(0) drain
// (global stores are fire-and-forget; global loads get per-use waits from the compiler)
#define BAR_LGKM() do {                                        \
  __builtin_amdgcn_sched_barrier(0);                           \
  asm volatile("s_waitcnt lgkmcnt(0)" ::: "memory");           \
  __builtin_amdgcn_s_barrier();                                \
  __builtin_amdgcn_sched_barrier(0);                           \
} while(0)

// intra-wave LDS fence (producer lanes -> consumer lanes of the SAME wave)
#define FENCE_LGKM() do {                                      \
  __builtin_amdgcn_sched_barrier(0);                           \
  asm volatile("s_waitcnt lgkmcnt(0)" ::: "memory");           \
  __builtin_amdgcn_sched_barrier(0);                           \
} while(0)

// ================= prep 1: W_comb[2048][16] = W_ih[:, :512] · Wcat, + folded x-bias ===========
__global__ void k_fold(const float* __restrict__ W_ih,
                       const float* __restrict__ W_cmd, const float* __restrict__ b_cmd,
                       const float* __restrict__ W_coord, const float* __restrict__ b_coord,
                       const float* __restrict__ W_head, const float* __restrict__ b_head,
                       float* __restrict__ W_comb, float* __restrict__ b_fold)
{
  const int g = blockIdx.x;      // 2048
  const int lane = threadIdx.x;  // 64
  float p[17];
  #pragma unroll
  for (int k=0;k<17;++k) p[k]=0.f;
  for (int d = lane; d < DM; d += 64){
    float w = W_ih[g*640 + d];
    #pragma unroll
    for (int c=0;c<6;++c)  p[c]    += w * W_cmd[d*6+c];
    #pragma unroll
    for (int c=0;c<8;++c)  p[6+c]  += w * W_coord[d*8+c];
    p[14] += w * W_head[d*2+0];
    p[15] += w * W_head[d*2+1];
    p[16] += w * (b_cmd[d] + b_coord[d] + b_head[d]);
  }
  #pragma unroll
  for (int k=0;k<17;++k){
    #pragma unroll
    for (int off=32; off>0; off>>=1) p[k] += __shfl_xor(p[k], off);
  }
  if (lane == 0){
    #pragma unroll
    for (int k=0;k<16;++k) W_comb[g*16+k] = p[k];
    b_fold[g] = p[16];
  }
}

// ================= prep 2: gate-B fp8, scaled xBSCALE, fragment-linear ======================
__global__ void k_bp(const float* __restrict__ Whh, const float* __restrict__ W_comb,
                     unsigned char* __restrict__ Bp)
{
  const int flat = blockIdx.x*256 + threadIdx.x;   // 1280 blocks -> 327680
  const int j   = flat & 7;
  const int l   = (flat >> 3) & 63;
  const int idx = flat >> 9;                        // n*5 + kc
  const int n   = idx / 5;
  const int kc  = idx - n*5;
  const int g   = n*16 + (l & 15);
  const int k   = kc*32 + ((l >> 4) & 3)*8 + j;
  float v = (k < 128) ? Whh[g*PR + k] : ((k < 144) ? W_comb[g*16 + (k-128)] : 0.f);
  Bp[flat] = f2fp8(BSCALE * v);
}

// ================= prep 3: W_hr bf16 fragment-linear (8 tiles) ==============================
__global__ void k_wr2(const float* __restrict__ Whr, __hip_bfloat16* __restrict__ Wr2)
{
  const int flat = blockIdx.x*256 + threadIdx.x;   // 256 blocks: 8*16*64*8 = 65536
  const int j   = flat & 7;
  const int l   = (flat >> 3) & 63;
  const int kc  = (flat >> 9) & 15;
  const int tn  = flat >> 13;                       // 0..7
  const int row = tn*16 + (l & 15);                 // p < 128
  const int d   = kc*32 + ((l >> 4) & 3)*8 + j;
  Wr2[flat] = __float2bfloat16(Whr[row*DM + d]);
}

// ================= prep 4: Wh2[t][p] frag-linear: t<14 = ln_g*Wo~; t==14 = 1 (Σh col) ======
// head_t = rs*(P_t - mu*S1_t) + S2_t, P = rawh · Wh2^T ; mu from P_14 = Σh
__global__ void k_wh2(const float* __restrict__ ln_g, const float* __restrict__ ln_b,
                      const float* __restrict__ Wocmd, const float* __restrict__ Wocoord,
                      const float* __restrict__ bocmd, const float* __restrict__ bocoord,
                      __hip_bfloat16* __restrict__ Wh2, float* __restrict__ S12)
{
  if (blockIdx.x == 8){
    const int t = threadIdx.x;
    if (t >= 14) return;
    float s1 = 0.f, s2 = 0.f;
    for (int p=0; p<PR; ++p){
      float wo;
      if (t < 6) wo = Wocmd[t*PR + p];
      else {
        wo = Wocoord[(t-6)*134 + p];
        for (int k=0;k<6;++k) wo += Wocoord[(t-6)*134 + 128 + k]*Wocmd[k*PR + p];
      }
      s1 += ln_g[p]*wo;
      s2 += ln_b[p]*wo;
    }
    if (t < 6) s2 += bocmd[t];
    else {
      s2 += bocoord[t-6];
      for (int k=0;k<6;++k) s2 += Wocoord[(t-6)*134 + 128 + k]*bocmd[k];
    }
    S12[t] = s1; S12[16+t] = s2;
    return;
  }
  const int flat = blockIdx.x*256 + threadIdx.x;   // 0..2047
  const int j  = flat & 7;
  const int l  = (flat >> 3) & 63;
  const int kc = flat >> 9;                         // 0..3
  const int t  = l & 15;
  const int p  = kc*32 + ((l >> 4) & 3)*8 + j;
  float v = 0.f;
  if (t < 6) v = Wocmd[t*PR + p];
  else if (t < 14){
    v = Wocoord[(t-6)*134 + p];
    for (int k=0;k<6;++k) v += Wocoord[(t-6)*134 + 128 + k]*Wocmd[k*PR + p];
  }
  else if (t == 14) v = 1.0f;                       // Σh column (raw, unscaled)
  Wh2[flat] = __float2bfloat16(t == 14 ? v : ln_g[p] * v);
}

// ================= prep 5: ctxB[b][g] = b_ih+b_hh+b_fold + ctx[b]·W_ih[g,512:] (b-major) ====
__global__ void k_ctx(const float* __restrict__ context, const float* __restrict__ W_ih,
                      const float* __restrict__ b_ih, const float* __restrict__ b_hh,
                      const float* __restrict__ b_fold, float* __restrict__ ctxB)
{
  const int idx = blockIdx.x*256 + threadIdx.x;   // 2048 blocks * 256 = B_*G4
  const int b = idx >> 11;
  const int g = idx & 2047;
  float a = b_ih[g] + b_hh[g] + b_fold[g];
  const float4* cp = reinterpret_cast<const float4*>(context + b*LAT);
  const float4* wp = reinterpret_cast<const float4*>(W_ih + g*640 + DM);
  #pragma unroll 8
  for (int q=0; q<LAT/4; ++q){
    float4 c = cp[q], w = wp[q];
    a += c.x*w.x + c.y*w.y + c.z*w.z + c.w*w.w;
  }
  ctxB[idx] = a;   // [b][g]
}

// ======== fused MFMA LSTM scan: 2 lgkm-only barriers/step, intra-wave G->A, hidden x-load ====
__global__ __launch_bounds__(512, 2)
void k_scan(const float* __restrict__ x_std,
            const float* __restrict__ ctxB,
            const unsigned char* __restrict__ Bp,
            const __hip_bfloat16* __restrict__ Wr2,
            const __hip_bfloat16* __restrict__ Wh2,
            const float* __restrict__ S12,
            float* __restrict__ out_cmd, float* __restrict__ out_coord)
{
  const int tid = threadIdx.x;
  const int w   = tid >> 6;        // wave 0..7
  const int l   = tid & 63;
  const int l15 = l & 15;
  const int lq  = l >> 4;          // 0..3
  const int b0  = blockIdx.x * NB;

  __shared__ __align__(16) __hip_bfloat16 Wr2L[8*6*64*8];   // 48 KB: Wr2 kc 10..15 per wave
  __shared__ __align__(8)  unsigned char  Bwp[128*32*8];    // 32 KB: kc4 packed (real half)
  __shared__ __align__(16) float Graw[G4*NB];               // 32 KB: raw gate sums [g][b]
  __shared__ __align__(16) __hip_bfloat16 HF[16*520];       // 16.6 KB [b][d], rows 4-15 zero
  __shared__ __align__(16) __hip_bfloat16 Wh2L[4*64*8];     // 4 KB: head B-frags
  __shared__ __align__(8)  unsigned char  A8[16*168];       // 2.7 KB [b][k] fp8, rows 4-15 zero
  __shared__ __align__(16) __hip_bfloat16 HN[16*136];       // 4.3 KB raw h bf16, rows 4-15 zero

  // ---- gate weights kc=0..3 -> 128 regs (AGPR) ----
  long bp[4][4][4];
  {
    const long* Bpl = reinterpret_cast<const long*>(Bp);
    #pragma unroll
    for (int dtl=0; dtl<4; ++dtl)
      #pragma unroll
      for (int gt=0; gt<4; ++gt)
        #pragma unroll
        for (int kc=0; kc<4; ++kc){
          const int n = gt*32 + w*4 + dtl;
          bp[dtl][gt][kc] = Bpl[(n*5 + kc)*64 + l];
        }
  }
  // ---- Wr2 kc 0..9 -> 40 VGPRs ----
  uint4 wrr[10];
  {
    const uint4* Wr2u4 = reinterpret_cast<const uint4*>(Wr2);
    #pragma unroll
    for (int kk=0; kk<10; ++kk)
      wrr[kk] = Wr2u4[(w*16 + kk)*64 + l];
  }
  // ---- stage Wr2 kc 10..15 -> LDS (3072 uint4) ----
  {
    const uint4* Wr2u4 = reinterpret_cast<const uint4*>(Wr2);
    uint4* dst = reinterpret_cast<uint4*>(Wr2L);
    for (int i = tid; i < 3072; i += 512){
      const int wi = i / 384;
      const int kk = (i - wi*384) >> 6;
      const int ll = i & 63;
      dst[i] = Wr2u4[(wi*16 + 10 + kk)*64 + ll];
    }
  }
  // ---- stage kc4 packed -> LDS (real half: orig lanes 0..31) ----
  {
    const long* Bpl = reinterpret_cast<const long*>(Bp);
    long* dst = reinterpret_cast<long*>(Bwp);
    for (int i = tid; i < 4096; i += 512)
      dst[i] = Bpl[((i>>5)*5 + 4)*64 + (i & 31)];
  }
  // ---- stage Wh2 -> LDS (256 uint4) ----
  {
    const uint4* src = reinterpret_cast<const uint4*>(Wh2);
    uint4* dst = reinterpret_cast<uint4*>(Wh2L);
    for (int i = tid; i < 256; i += 512) dst[i] = src[i];
  }
  // ---- ctx -> 16 regs/thread (step-invariant; thread owns d = tid) ----
  float cx[4][4];
  #pragma unroll
  for (int gt=0; gt<4; ++gt)
    #pragma unroll
    for (int b=0; b<NB; ++b)
      cx[gt][b] = ctxB[(b0+b)*G4 + gt*512 + tid];

  // ---- S1/S2 for head lanes ----
  float S1k = 0.f, S2k = 0.f;
  if (l15 < 14){ S1k = S12[l15]; S2k = S12[16 + l15]; }

  // ---- zero LDS state (rows 4-15 stay zero forever) ----
  for (int i = tid; i < 16*520/2; i += 512) reinterpret_cast<unsigned*>(HF)[i] = 0u;
  for (int i = tid; i < 16*168/4; i += 512) reinterpret_cast<unsigned*>(A8)[i] = 0u;
  for (int i = tid; i < 16*136/2; i += 512) reinterpret_cast<unsigned*>(HN)[i] = 0u;
  __syncthreads();
  if (tid < 64){
    const int b = tid >> 4, c = tid & 15;
    A8[b*168 + 128 + c] = f2fp8(ASCALE * x_std[(b0+b)*S_*16 + c]);   // x at s=0
  }

  float c_st[NB] = {0.f, 0.f, 0.f, 0.f};   // cell state: thread owns dim d = tid
  __syncthreads();

  const f32x4 zz = {0.f, 0.f, 0.f, 0.f};
  const int a_off = l15*168 + lq*8;
  const long* Bwpl = reinterpret_cast<const long*>(Bwp);
  const int xb = tid >> 4, xc = tid & 15;   // x-prefetch coords (tid<64)

  for (int s = 0; s < S_; ++s){
    // ---- x(s+1): ISSUE EARLY (consumed ~3000cyc later, post-Bar2 -> HBM latency hidden) ----
    float xv = 0.f;
    if (s+1 < S_ && tid < 64) xv = x_std[((b0+xb)*S_ + s+1)*16 + xc];

    // ==== deferred heads + LN moments for step s-1 (wave 7; overlaps other waves' G) ====
    if (w == 7 && s > 0){
      __builtin_amdgcn_s_setprio(1);
      f32x4 hd = zz, ss = zz;
      #pragma unroll
      for (int kc=0;kc<4;++kc){
        bf16x8 ha = ldg8(&HN[l15*136 + kc*32 + lq*8]);
        bf16x8 hb = ldg8(&Wh2L[(kc*64 + l)*8]);
        hd = __builtin_amdgcn_mfma_f32_16x16x32_bf16(ha, hb, hd, 0,0,0);
        ss = __builtin_amdgcn_mfma_f32_16x16x32_bf16(ha, ha, ss, 0,0,0);
      }
      // mu from Σh column (col 14), Σh² from self-MFMA diagonal
      float mu[NB], rs[NB];
      #pragma unroll
      for (int r=0;r<NB;++r){
        const float sh = __shfl(hd[r], 14);          // lane (lq=0,l15=14), reg r
        const float s2 = __shfl(ss[r], r);           // lane (lq=0,l15=r),  reg r
        const float m  = sh * (1.f/128.f);
        const float vr = s2 * (1.f/128.f) - m*m;
        mu[r] = m; rs[r] = rsqrtf(vr + 1e-5f);
      }
      if (lq == 0){
        #pragma unroll
        for (int r=0;r<NB;++r){
          const float v = rs[r]*(hd[r] - mu[r]*S1k) + S2k;
          const int b = b0 + r;
          if (l15 < 6)       out_cmd[(b*S_ + (s-1))*6 + l15] = v;
          else if (l15 < 14) out_coord[(b*S_ + (s-1))*8 + (l15-6)] = v;
        }
      }
      __builtin_amdgcn_s_setprio(0);
    }

    // ======== Phase G: raw gates = A8·B (fp8 MFMA, weights on-CU) -> Graw ========
    long afr[5];
    #pragma unroll
    for (int kc=0;kc<5;++kc)
      afr[kc] = *reinterpret_cast<const long*>(&A8[a_off + kc*32]);

    #pragma unroll
    for (int dtl=0; dtl<4; ++dtl){
      const int dt = w*4 + dtl;
      long bl[4];
      #pragma unroll
      for (int gt=0; gt<4; ++gt){
        const long t0 = Bwpl[(gt*32 + dt)*32 + (l & 31)];
        bl[gt] = (lq < 2) ? t0 : 0L;
      }
      f32x4 az[4] = {zz, zz, zz, zz};
      #pragma unroll
      for (int kc=0;kc<4;++kc)
        #pragma unroll
        for (int gt=0; gt<4; ++gt)
          az[gt] = __builtin_amdgcn_mfma_f32_16x16x32_fp8_fp8(afr[kc], bp[dtl][gt][kc], az[gt], 0,0,0);
      #pragma unroll
      for (int gt=0; gt<4; ++gt)
        az[gt] = __builtin_amdgcn_mfma_f32_16x16x32_fp8_fp8(afr[4], bl[gt], az[gt], 0,0,0);
      if (lq == 0){
        #pragma unroll
        for (int gt=0; gt<4; ++gt)
          *reinterpret_cast<f32x4*>(&Graw[(gt*512 + dt*16 + l15)*NB]) = az[gt];
      }
    }
    // G -> A is INTRA-WAVE (gate g==d mod 512 is produced by wave d>>6): no barrier needed
    FENCE_LGKM();

    // ======== Phase A: activations distributed (thread owns d = tid, 4 batches) ========
    {
      const int d = tid;
      f32x4 gv[4];
      #pragma unroll
      for (int gt=0; gt<4; ++gt)
        gv[gt] = *reinterpret_cast<const f32x4*>(&Graw[(gt*512 + d)*NB]);
      #pragma unroll
      for (int b=0; b<NB; ++b){
        const float iv = sigf  (gv[0][b]*DSCALE + cx[0][b]);
        const float fv = sigf  (gv[1][b]*DSCALE + cx[1][b]);
        const float gg = tanhft(gv[2][b]*DSCALE + cx[2][b]);
        const float ov = sigf  (gv[3][b]*DSCALE + cx[3][b]);
        const float cc = fv*c_st[b] + iv*gg;
        c_st[b] = cc;
        HF[b*520 + d] = __float2bfloat16(ov*tanhft(cc));
      }
    }
    BAR_LGKM();  // Bar2: HF ready (cross-wave); no vmcnt drain

    // ======== Phase R: h = h_full · W_hr^T (B: 10 frags regs + 6 LDS; zero-padded A) ========
    // x(s+1) -> A8 (safe: all waves' Phase-G A8 reads finished before Bar2)
    if (s+1 < S_ && tid < 64)
      A8[xb*168 + 128 + xc] = f2fp8(ASCALE * xv);

    f32x4 aA = zz, aB = zz;
    #pragma unroll
    for (int kk=0; kk<16; ++kk){
      bf16x8 a2 = ldg8(&HF[l15*520 + kk*32 + lq*8]);
      bf16x8 b2;
      if (kk < 10) b2 = __builtin_bit_cast(bf16x8, wrr[kk]);
      else         b2 = ldg8(&Wr2L[((w*6 + (kk-10))*64 + l)*8]);
      if (kk & 1) aB = __builtin_amdgcn_mfma_f32_16x16x32_bf16(a2, b2, aB, 0,0,0);
      else        aA = __builtin_amdgcn_mfma_f32_16x16x32_bf16(a2, b2, aA, 0,0,0);
    }
    f32x4 acc2 = aA + aB;    // row (lq==0, r) = batch r, col p = w*16+l15

    // raw h -> A8 (fp8 recurrent state) and HN (bf16 for deferred heads/LN moments)
    if (lq == 0){
      #pragma unroll
      for (int r=0;r<NB;++r){
        const float h = acc2[r];
        HN[r*136 + w*16 + l15] = __float2bfloat16(h);
        A8[r*168 + w*16 + l15] = f2fp8(ASCALE * h);
      }
    }
    BAR_LGKM();  // Bar3: A8/HN ready for next step (cross-wave); no vmcnt drain
  }

  // ======== epilogue: heads for s = S_-1 (wave 7) ========
  if (w == 7){
    f32x4 hd = zz, ss = zz;
    #pragma unroll
    for (int kc=0;kc<4;++kc){
      bf16x8 ha = ldg8(&HN[l15*136 + kc*32 + lq*8]);
      bf16x8 hb = ldg8(&Wh2L[(kc*64 + l)*8]);
      hd = __builtin_amdgcn_mfma_f32_16x16x32_bf16(ha, hb, hd, 0,0,0);
      ss = __builtin_amdgcn_mfma_f32_16x16x32_bf16(ha, ha, ss, 0,0,0);
    }
    float mu[NB], rs[NB];
    #pragma unroll
    for (int r=0;r<NB;++r){
      const float sh = __shfl(hd[r], 14);
      const float s2 = __shfl(ss[r], r);
      const float m  = sh * (1.f/128.f);
      const float vr = s2 * (1.f/128.f) - m*m;
      mu[r] = m; rs[r] = rsqrtf(vr + 1e-5f);
    }
    if (lq == 0){
      #pragma unroll
      for (int r=0;r<NB;++r){
        const float v = rs[r]*(hd[r] - mu[r]*S1k) + S2k;
        const int b = b0 + r;
        if (l15 < 6)       out_cmd[(b*S_ + (S_-1))*6 + l15] = v;
        else if (l15 < 14) out_coord[(b*S_ + (S_-1))*8 + (l15-6)] = v;
      }
    }
  }
}

extern "C" void kernel_launch(void* const* d_in, const int* in_sizes, int n_in,
                              void* d_out, int out_size, void* d_ws, size_t ws_size,
                              hipStream_t stream)
{
  const float* x_std       = (const float*)d_in[0];
  const float* context     = (const float*)d_in[1];
  const float* W_cmd       = (const float*)d_in[2];
  const float* b_cmd       = (const float*)d_in[3];
  const float* W_coord     = (const float*)d_in[4];
  const float* b_coord     = (const float*)d_in[5];
  const float* W_head      = (const float*)d_in[6];
  const float* b_head      = (const float*)d_in[7];
  const float* W_ih        = (const float*)d_in[8];
  const float* W_hh        = (const float*)d_in[9];
  const float* W_hr        = (const float*)d_in[10];
  const float* b_ih        = (const float*)d_in[11];
  const float* b_hh        = (const float*)d_in[12];
  const float* ln_g        = (const float*)d_in[13];
  const float* ln_b        = (const float*)d_in[14];
  const float* W_out_cmd   = (const float*)d_in[15];
  const float* b_out_cmd   = (const float*)d_in[16];
  const float* W_out_coord = (const float*)d_in[17];
  const float* b_out_coord = (const float*)d_in[18];

  float* out = (float*)d_out;
  char*  ws  = (char*)d_ws;

  unsigned char*  Bp   = (unsigned char*)(ws);              // 327680
  __hip_bfloat16* Wr2  = (__hip_bfloat16*)(ws + 327680);    // 131072 -> 458752
  __hip_bfloat16* Wh2  = (__hip_bfloat16*)(ws + 458752);    // 4096   -> 462848
  float* S12           = (float*)(ws + 462848);             // 128    -> 462976
  float* b_fold        = (float*)(ws + 462976);             // 8192   -> 471168
  float* W_comb        = (float*)(ws + 471168);             // 131072 -> 602240 (dead after k_bp)
  float* ctxB          = (float*)(ws + 602240);             // 2097152 -> 2699392 total

  k_fold<<<dim3(G4), dim3(64), 0, stream>>>(W_ih, W_cmd, b_cmd, W_coord, b_coord,
                                            W_head, b_head, W_comb, b_fold);
  k_bp<<<dim3(1280), dim3(256), 0, stream>>>(W_hh, W_comb, Bp);
  k_wr2<<<dim3(256), dim3(256), 0, stream>>>(W_hr, Wr2);
  k_wh2<<<dim3(9), dim3(256), 0, stream>>>(ln_g, ln_b, W_out_cmd, W_out_coord,
                                           b_out_cmd, b_out_coord, Wh2, S12);
  k_ctx<<<dim3((B_*G4)/256), dim3(256), 0, stream>>>(context, W_ih, b_ih, b_hh,
                                                     b_fold, ctxB);
  k_scan<<<dim3(B_/NB), dim3(512), 0, stream>>>(x_std, ctxB, Bp, Wr2, Wh2, S12,
                                                out, out + B_*S_*6);
}

// Round 12
// 823.583 us; speedup vs baseline: 2.6224x; 1.1981x over previous
//
#include <hip/hip_runtime.h>
#include <hip/hip_bf16.h>
#include <stdint.h>

#define B_   256
#define S_   256
#define DM   512
#define G4   2048
#define LAT  128
#define PR   128
#define NB   2      // batches per block -> 128 blocks

typedef __bf16 bf16x8 __attribute__((ext_vector_type(8)));
typedef float  f32x4  __attribute__((ext_vector_type(4)));
typedef float  f32x2  __attribute__((ext_vector_type(2)));

__device__ __forceinline__ bf16x8 ldg8(const __hip_bfloat16* p){
  uint4 v = *reinterpret_cast<const uint4*>(p);
  return __builtin_bit_cast(bf16x8, v);
}
__device__ __forceinline__ float sigf(float x){ return 1.f/(1.f+__expf(-x)); }
__device__ __forceinline__ float tanhft(float x){ return 1.f - 2.f/(__expf(2.f*x)+1.f); }
__device__ __forceinline__ unsigned char f2fp8(float x){
  return (unsigned char)(__builtin_amdgcn_cvt_pk_fp8_f32(x, x, 0, false) & 0xff);
}

#define BSCALE 64.f
#define ASCALE 8.f
#define DSCALE (1.f/512.f)

// lgkm-only barrier: LDS producers drained, s_barrier, NO vmcnt(0) drain
#define BAR_LGKM() do {                                        \
  __builtin_amdgcn_sched_barrier(0);                           \
  asm volatile("s_waitcnt lgkmcnt(0)" ::: "memory");           \
  __builtin_amdgcn_s_barrier();                                \
  __builtin_amdgcn_sched_barrier(0);                           \
} while(0)

// intra-wave LDS fence
#define FENCE_LGKM() do {                                      \
  __builtin_amdgcn_sched_barrier(0);                           \
  asm volatile("s_waitcnt lgkmcnt(0)" ::: "memory");           \
  __builtin_amdgcn_sched_barrier(0);                           \
} while(0)

// ================= prep 1: W_comb[2048][16] = W_ih[:, :512] · Wcat, + folded x-bias ===========
__global__ void k_fold(const float* __restrict__ W_ih,
                       const float* __restrict__ W_cmd, const float* __restrict__ b_cmd,
                       const float* __restrict__ W_coord, const float* __restrict__ b_coord,
                       const float* __restrict__ W_head, const float* __restrict__ b_head,
                       float* __restrict__ W_comb, float* __restrict__ b_fold)
{
  const int g = blockIdx.x;      // 2048
  const int lane = threadIdx.x;  // 64
  float p[17];
  #pragma unroll
  for (int k=0;k<17;++k) p[k]=0.f;
  for (int d = lane; d < DM; d += 64){
    float w = W_ih[g*640 + d];
    #pragma unroll
    for (int c=0;c<6;++c)  p[c]    += w * W_cmd[d*6+c];
    #pragma unroll
    for (int c=0;c<8;++c)  p[6+c]  += w * W_coord[d*8+c];
    p[14] += w * W_head[d*2+0];
    p[15] += w * W_head[d*2+1];
    p[16] += w * (b_cmd[d] + b_coord[d] + b_head[d]);
  }
  #pragma unroll
  for (int k=0;k<17;++k){
    #pragma unroll
    for (int off=32; off>0; off>>=1) p[k] += __shfl_xor(p[k], off);
  }
  if (lane == 0){
    #pragma unroll
    for (int k=0;k<16;++k) W_comb[g*16+k] = p[k];
    b_fold[g] = p[16];
  }
}

// ================= prep 2: gate-B fp8, scaled xBSCALE, fragment-linear ======================
__global__ void k_bp(const float* __restrict__ Whh, const float* __restrict__ W_comb,
                     unsigned char* __restrict__ Bp)
{
  const int flat = blockIdx.x*256 + threadIdx.x;   // 1280 blocks -> 327680
  const int j   = flat & 7;
  const int l   = (flat >> 3) & 63;
  const int idx = flat >> 9;                        // n*5 + kc
  const int n   = idx / 5;
  const int kc  = idx - n*5;
  const int g   = n*16 + (l & 15);
  const int k   = kc*32 + ((l >> 4) & 3)*8 + j;
  float v = (k < 128) ? Whh[g*PR + k] : ((k < 144) ? W_comb[g*16 + (k-128)] : 0.f);
  Bp[flat] = f2fp8(BSCALE * v);
}

// ================= prep 3: W_hr bf16 fragment-linear (8 tiles) ==============================
__global__ void k_wr2(const float* __restrict__ Whr, __hip_bfloat16* __restrict__ Wr2)
{
  const int flat = blockIdx.x*256 + threadIdx.x;   // 256 blocks: 8*16*64*8 = 65536
  const int j   = flat & 7;
  const int l   = (flat >> 3) & 63;
  const int kc  = (flat >> 9) & 15;
  const int tn  = flat >> 13;                       // 0..7
  const int row = tn*16 + (l & 15);                 // p < 128
  const int d   = kc*32 + ((l >> 4) & 3)*8 + j;
  Wr2[flat] = __float2bfloat16(Whr[row*DM + d]);
}

// ================= prep 4: Wh2[t][p] frag-linear: t<14 = ln_g*Wo~; t==14 = 1 (Σh col) ======
__global__ void k_wh2(const float* __restrict__ ln_g, const float* __restrict__ ln_b,
                      const float* __restrict__ Wocmd, const float* __restrict__ Wocoord,
                      const float* __restrict__ bocmd, const float* __restrict__ bocoord,
                      __hip_bfloat16* __restrict__ Wh2, float* __restrict__ S12)
{
  if (blockIdx.x == 8){
    const int t = threadIdx.x;
    if (t >= 14) return;
    float s1 = 0.f, s2 = 0.f;
    for (int p=0; p<PR; ++p){
      float wo;
      if (t < 6) wo = Wocmd[t*PR + p];
      else {
        wo = Wocoord[(t-6)*134 + p];
        for (int k=0;k<6;++k) wo += Wocoord[(t-6)*134 + 128 + k]*Wocmd[k*PR + p];
      }
      s1 += ln_g[p]*wo;
      s2 += ln_b[p]*wo;
    }
    if (t < 6) s2 += bocmd[t];
    else {
      s2 += bocoord[t-6];
      for (int k=0;k<6;++k) s2 += Wocoord[(t-6)*134 + 128 + k]*bocmd[k];
    }
    S12[t] = s1; S12[16+t] = s2;
    return;
  }
  const int flat = blockIdx.x*256 + threadIdx.x;   // 0..2047
  const int j  = flat & 7;
  const int l  = (flat >> 3) & 63;
  const int kc = flat >> 9;                         // 0..3
  const int t  = l & 15;
  const int p  = kc*32 + ((l >> 4) & 3)*8 + j;
  float v = 0.f;
  if (t < 6) v = Wocmd[t*PR + p];
  else if (t < 14){
    v = Wocoord[(t-6)*134 + p];
    for (int k=0;k<6;++k) v += Wocoord[(t-6)*134 + 128 + k]*Wocmd[k*PR + p];
  }
  else if (t == 14) v = 1.0f;                       // Σh column
  Wh2[flat] = __float2bfloat16(t == 14 ? v : ln_g[p] * v);
}

// ================= prep 5: ctxB[b][g] = b_ih+b_hh+b_fold + ctx[b]·W_ih[g,512:] (b-major) ====
__global__ void k_ctx(const float* __restrict__ context, const float* __restrict__ W_ih,
                      const float* __restrict__ b_ih, const float* __restrict__ b_hh,
                      const float* __restrict__ b_fold, float* __restrict__ ctxB)
{
  const int idx = blockIdx.x*256 + threadIdx.x;   // 2048 blocks * 256 = B_*G4
  const int b = idx >> 11;
  const int g = idx & 2047;
  float a = b_ih[g] + b_hh[g] + b_fold[g];
  const float4* cp = reinterpret_cast<const float4*>(context + b*LAT);
  const float4* wp = reinterpret_cast<const float4*>(W_ih + g*640 + DM);
  #pragma unroll 8
  for (int q=0; q<LAT/4; ++q){
    float4 c = cp[q], w = wp[q];
    a += c.x*w.x + c.y*w.y + c.z*w.z + c.w*w.w;
  }
  ctxB[idx] = a;   // [b][g]
}

// ==== fused MFMA LSTM scan: NB=2, zero-row broadcast aliasing, all-wave redundant heads =====
__global__ __launch_bounds__(512, 2)
void k_scan(const float* __restrict__ x_std,
            const float* __restrict__ ctxB,
            const unsigned char* __restrict__ Bp,
            const __hip_bfloat16* __restrict__ Wr2,
            const __hip_bfloat16* __restrict__ Wh2,
            const float* __restrict__ S12,
            float* __restrict__ out_cmd, float* __restrict__ out_coord)
{
  const int tid = threadIdx.x;
  const int w   = tid >> 6;        // wave 0..7
  const int l   = tid & 63;
  const int l15 = l & 15;
  const int lq  = l >> 4;          // 0..3
  const int b0  = blockIdx.x * NB;
  const int rz  = (l15 < NB) ? l15 : NB;   // zero-row alias: rows >= NB broadcast row NB (all-zero)

  __shared__ __align__(16) __hip_bfloat16 Wr2L[8*6*64*8];   // 48 KB: Wr2 kc 10..15 per wave
  __shared__ __align__(8)  unsigned char  Bwp[128*32*8];    // 32 KB: kc4 packed (real half)
  __shared__ __align__(16) float Graw[G4*NB];               // 16 KB: raw gate sums [g][b]
  __shared__ __align__(16) __hip_bfloat16 HF[16*520];       // rows 0..NB-1 real, rest zero
  __shared__ __align__(16) __hip_bfloat16 Wh2L[4*64*8];     // 4 KB: head B-frags
  __shared__ __align__(8)  unsigned char  A8[16*168];       // rows 0..NB-1 real, rest zero
  __shared__ __align__(16) __hip_bfloat16 HN[16*136];       // rows 0..NB-1 real, rest zero

  // ---- gate weights kc=0..3 -> 128 regs (AGPR) ----
  long bp[4][4][4];
  {
    const long* Bpl = reinterpret_cast<const long*>(Bp);
    #pragma unroll
    for (int dtl=0; dtl<4; ++dtl)
      #pragma unroll
      for (int gt=0; gt<4; ++gt)
        #pragma unroll
        for (int kc=0; kc<4; ++kc){
          const int n = gt*32 + w*4 + dtl;
          bp[dtl][gt][kc] = Bpl[(n*5 + kc)*64 + l];
        }
  }
  // ---- Wr2 kc 0..9 -> 40 VGPRs ----
  uint4 wrr[10];
  {
    const uint4* Wr2u4 = reinterpret_cast<const uint4*>(Wr2);
    #pragma unroll
    for (int kk=0; kk<10; ++kk)
      wrr[kk] = Wr2u4[(w*16 + kk)*64 + l];
  }
  // ---- stage Wr2 kc 10..15 -> LDS (3072 uint4) ----
  {
    const uint4* Wr2u4 = reinterpret_cast<const uint4*>(Wr2);
    uint4* dst = reinterpret_cast<uint4*>(Wr2L);
    for (int i = tid; i < 3072; i += 512){
      const int wi = i / 384;
      const int kk = (i - wi*384) >> 6;
      const int ll = i & 63;
      dst[i] = Wr2u4[(wi*16 + 10 + kk)*64 + ll];
    }
  }
  // ---- stage kc4 packed -> LDS (real half: orig lanes 0..31) ----
  {
    const long* Bpl = reinterpret_cast<const long*>(Bp);
    long* dst = reinterpret_cast<long*>(Bwp);
    for (int i = tid; i < 4096; i += 512)
      dst[i] = Bpl[((i>>5)*5 + 4)*64 + (i & 31)];
  }
  // ---- stage Wh2 -> LDS (256 uint4) ----
  {
    const uint4* src = reinterpret_cast<const uint4*>(Wh2);
    uint4* dst = reinterpret_cast<uint4*>(Wh2L);
    for (int i = tid; i < 256; i += 512) dst[i] = src[i];
  }
  // ---- ctx -> regs (step-invariant; thread owns d = tid) ----
  float cx[4][NB];
  #pragma unroll
  for (int gt=0; gt<4; ++gt)
    #pragma unroll
    for (int b=0; b<NB; ++b)
      cx[gt][b] = ctxB[(b0+b)*G4 + gt*512 + tid];

  // ---- S1/S2 for head lanes ----
  float S1k = 0.f, S2k = 0.f;
  if (l15 < 14){ S1k = S12[l15]; S2k = S12[16 + l15]; }

  // ---- zero LDS state (rows NB..15 stay zero forever) ----
  for (int i = tid; i < 16*520/2; i += 512) reinterpret_cast<unsigned*>(HF)[i] = 0u;
  for (int i = tid; i < 16*168/4; i += 512) reinterpret_cast<unsigned*>(A8)[i] = 0u;
  for (int i = tid; i < 16*136/2; i += 512) reinterpret_cast<unsigned*>(HN)[i] = 0u;
  __syncthreads();
  if (tid < NB*16){
    const int b = tid >> 4, c = tid & 15;
    A8[b*168 + 128 + c] = f2fp8(ASCALE * x_std[(b0+b)*S_*16 + c]);   // x at s=0
  }

  float c_st[NB];
  #pragma unroll
  for (int b=0;b<NB;++b) c_st[b] = 0.f;
  __syncthreads();

  const f32x4 zz = {0.f, 0.f, 0.f, 0.f};
  const int a_off  = rz*168 + lq*8;        // broadcast-aliased A8 read base
  const int hf_off = rz*520 + lq*8;        // broadcast-aliased HF read base
  const int hn_off = rz*136 + lq*8;        // broadcast-aliased HN read base
  const long* Bwpl = reinterpret_cast<const long*>(Bwp);
  const int xb = tid >> 4, xc = tid & 15;  // x-prefetch coords (tid < NB*16)

  for (int s = 0; s < S_; ++s){
    // ---- x(s+1): ISSUE EARLY (consumed post-Bar2 -> HBM latency hidden) ----
    float xv = 0.f;
    if (s+1 < S_ && tid < NB*16) xv = x_std[((b0+xb)*S_ + s+1)*16 + xc];

    // ==== heads + LN moments for step s-1: ALL waves compute (no skew), wave 7 stores ====
    if (s > 0){
      f32x4 hd = zz, ss = zz;
      #pragma unroll
      for (int kc=0;kc<4;++kc){
        bf16x8 ha = ldg8(&HN[hn_off + kc*32]);
        bf16x8 hb = ldg8(&Wh2L[(kc*64 + l)*8]);
        hd = __builtin_amdgcn_mfma_f32_16x16x32_bf16(ha, hb, hd, 0,0,0);
        ss = __builtin_amdgcn_mfma_f32_16x16x32_bf16(ha, ha, ss, 0,0,0);
      }
      float mu[NB], rs[NB];
      #pragma unroll
      for (int r=0;r<NB;++r){
        const float sh = __shfl(hd[r], 14);          // Σh   (col 14 = ones)
        const float s2 = __shfl(ss[r], r);           // Σh²  (diagonal)
        const float m  = sh * (1.f/128.f);
        const float vr = s2 * (1.f/128.f) - m*m;
        mu[r] = m; rs[r] = rsqrtf(vr + 1e-5f);
      }
      if (w == 7 && lq == 0){
        #pragma unroll
        for (int r=0;r<NB;++r){
          const float v = rs[r]*(hd[r] - mu[r]*S1k) + S2k;
          const int b = b0 + r;
          if (l15 < 6)       out_cmd[(b*S_ + (s-1))*6 + l15] = v;
          else if (l15 < 14) out_coord[(b*S_ + (s-1))*8 + (l15-6)] = v;
        }
      }
    }

    // ======== Phase G: raw gates = A8·B (fp8 MFMA, weights on-CU) -> Graw ========
    long afr[5];
    #pragma unroll
    for (int kc=0;kc<5;++kc)
      afr[kc] = *reinterpret_cast<const long*>(&A8[a_off + kc*32]);

    #pragma unroll
    for (int dtl=0; dtl<4; ++dtl){
      const int dt = w*4 + dtl;
      long bl[4];
      #pragma unroll
      for (int gt=0; gt<4; ++gt){
        const long t0 = Bwpl[(gt*32 + dt)*32 + (l & 31)];
        bl[gt] = (lq < 2) ? t0 : 0L;
      }
      f32x4 az[4] = {zz, zz, zz, zz};
      #pragma unroll
      for (int kc=0;kc<4;++kc)
        #pragma unroll
        for (int gt=0; gt<4; ++gt)
          az[gt] = __builtin_amdgcn_mfma_f32_16x16x32_fp8_fp8(afr[kc], bp[dtl][gt][kc], az[gt], 0,0,0);
      #pragma unroll
      for (int gt=0; gt<4; ++gt)
        az[gt] = __builtin_amdgcn_mfma_f32_16x16x32_fp8_fp8(afr[4], bl[gt], az[gt], 0,0,0);
      if (lq == 0){
        #pragma unroll
        for (int gt=0; gt<4; ++gt){
          f32x2 t = {az[gt][0], az[gt][1]};
          *reinterpret_cast<f32x2*>(&Graw[(gt*512 + dt*16 + l15)*NB]) = t;
        }
      }
    }
    // G -> A is INTRA-WAVE: no barrier needed
    FENCE_LGKM();

    // ======== Phase A: activations distributed (thread owns d = tid, NB batches) ========
    {
      const int d = tid;
      f32x2 gv[4];
      #pragma unroll
      for (int gt=0; gt<4; ++gt)
        gv[gt] = *reinterpret_cast<const f32x2*>(&Graw[(gt*512 + d)*NB]);
      #pragma unroll
      for (int b=0; b<NB; ++b){
        const float iv = sigf  (gv[0][b]*DSCALE + cx[0][b]);
        const float fv = sigf  (gv[1][b]*DSCALE + cx[1][b]);
        const float gg = tanhft(gv[2][b]*DSCALE + cx[2][b]);
        const float ov = sigf  (gv[3][b]*DSCALE + cx[3][b]);
        const float cc = fv*c_st[b] + iv*gg;
        c_st[b] = cc;
        HF[b*520 + d] = __float2bfloat16(ov*tanhft(cc));
      }
    }
    BAR_LGKM();  // Bar2: HF ready (cross-wave); no vmcnt drain

    // ======== Phase R: h = h_full · W_hr^T (zero rows broadcast-aliased) ========
    if (s+1 < S_ && tid < NB*16)
      A8[xb*168 + 128 + xc] = f2fp8(ASCALE * xv);

    f32x4 aA = zz, aB = zz;
    #pragma unroll
    for (int kk=0; kk<16; ++kk){
      bf16x8 a2 = ldg8(&HF[hf_off + kk*32]);
      bf16x8 b2;
      if (kk < 10) b2 = __builtin_bit_cast(bf16x8, wrr[kk]);
      else         b2 = ldg8(&Wr2L[((w*6 + (kk-10))*64 + l)*8]);
      if (kk & 1) aB = __builtin_amdgcn_mfma_f32_16x16x32_bf16(a2, b2, aB, 0,0,0);
      else        aA = __builtin_amdgcn_mfma_f32_16x16x32_bf16(a2, b2, aA, 0,0,0);
    }
    f32x4 acc2 = aA + aB;    // row (lq==0, r) = batch r, col p = w*16+l15

    // raw h -> A8 (fp8 recurrent state) and HN (bf16 for heads/LN moments)
    if (lq == 0){
      #pragma unroll
      for (int r=0;r<NB;++r){
        const float h = acc2[r];
        HN[r*136 + w*16 + l15] = __float2bfloat16(h);
        A8[r*168 + w*16 + l15] = f2fp8(ASCALE * h);
      }
    }
    BAR_LGKM();  // Bar3: A8/HN ready for next step (cross-wave); no vmcnt drain
  }

  // ======== epilogue: heads for s = S_-1 (wave 7) ========
  if (w == 7){
    f32x4 hd = zz, ss = zz;
    #pragma unroll
    for (int kc=0;kc<4;++kc){
      bf16x8 ha = ldg8(&HN[hn_off + kc*32]);
      bf16x8 hb = ldg8(&Wh2L[(kc*64 + l)*8]);
      hd = __builtin_amdgcn_mfma_f32_16x16x32_bf16(ha, hb, hd, 0,0,0);
      ss = __builtin_amdgcn_mfma_f32_16x16x32_bf16(ha, ha, ss, 0,0,0);
    }
    float mu[NB], rs[NB];
    #pragma unroll
    for (int r=0;r<NB;++r){
      const float sh = __shfl(hd[r], 14);
      const float s2 = __shfl(ss[r], r);
      const float m  = sh * (1.f/128.f);
      const float vr = s2 * (1.f/128.f) - m*m;
      mu[r] = m; rs[r] = rsqrtf(vr + 1e-5f);
    }
    if (lq == 0){
      #pragma unroll
      for (int r=0;r<NB;++r){
        const float v = rs[r]*(hd[r] - mu[r]*S1k) + S2k;
        const int b = b0 + r;
        if (l15 < 6)       out_cmd[(b*S_ + (S_-1))*6 + l15] = v;
        else if (l15 < 14) out_coord[(b*S_ + (S_-1))*8 + (l15-6)] = v;
      }
    }
  }
}

extern "C" void kernel_launch(void* const* d_in, const int* in_sizes, int n_in,
                              void* d_out, int out_size, void* d_ws, size_t ws_size,
                              hipStream_t stream)
{
  const float* x_std       = (const float*)d_in[0];
  const float* context     = (const float*)d_in[1];
  const float* W_cmd       = (const float*)d_in[2];
  const float* b_cmd       = (const float*)d_in[3];
  const float* W_coord     = (const float*)d_in[4];
  const float* b_coord     = (const float*)d_in[5];
  const float* W_head      = (const float*)d_in[6];
  const float* b_head      = (const float*)d_in[7];
  const float* W_ih        = (const float*)d_in[8];
  const float* W_hh        = (const float*)d_in[9];
  const float* W_hr        = (const float*)d_in[10];
  const float* b_ih        = (const float*)d_in[11];
  const float* b_hh        = (const float*)d_in[12];
  const float* ln_g        = (const float*)d_in[13];
  const float* ln_b        = (const float*)d_in[14];
  const float* W_out_cmd   = (const float*)d_in[15];
  const float* b_out_cmd   = (const float*)d_in[16];
  const float* W_out_coord = (const float*)d_in[17];
  const float* b_out_coord = (const float*)d_in[18];

  float* out = (float*)d_out;
  char*  ws  = (char*)d_ws;

  unsigned char*  Bp   = (unsigned char*)(ws);              // 327680
  __hip_bfloat16* Wr2  = (__hip_bfloat16*)(ws + 327680);    // 131072 -> 458752
  __hip_bfloat16* Wh2  = (__hip_bfloat16*)(ws + 458752);    // 4096   -> 462848
  float* S12           = (float*)(ws + 462848);             // 128    -> 462976
  float* b_fold        = (float*)(ws + 462976);             // 8192   -> 471168
  float* W_comb        = (float*)(ws + 471168);             // 131072 -> 602240 (dead after k_bp)
  float* ctxB          = (float*)(ws + 602240);             // 2097152 -> 2699392 total

  k_fold<<<dim3(G4), dim3(64), 0, stream>>>(W_ih, W_cmd, b_cmd, W_coord, b_coord,
                                            W_head, b_head, W_comb, b_fold);
  k_bp<<<dim3(1280), dim3(256), 0, stream>>>(W_hh, W_comb, Bp);
  k_wr2<<<dim3(256), dim3(256), 0, stream>>>(W_hr, Wr2);
  k_wh2<<<dim3(9), dim3(256), 0, stream>>>(ln_g, ln_b, W_out_cmd, W_out_coord,
                                           b_out_cmd, b_out_coord, Wh2, S12);
  k_ctx<<<dim3((B_*G4)/256), dim3(256), 0, stream>>>(context, W_ih, b_ih, b_hh,
                                                     b_fold, ctxB);
  k_scan<<<dim3(B_/NB), dim3(512), 0, stream>>>(x_std, ctxB, Bp, Wr2, Wh2, S12,
                                                out, out + B_*S_*6);
}

// Round 13
// 722.144 us; speedup vs baseline: 2.9907x; 1.1405x over previous
//
#include <hip/hip_runtime.h>
#include <hip/hip_bf16.h>
#include <stdint.h>

#define B_   256
#define S_   256
#define DM   512
#define G4   2048
#define LAT  128
#define PR   128
#define NB   1      // batches per block -> 256 blocks

typedef __bf16 bf16x8 __attribute__((ext_vector_type(8)));
typedef float  f32x4  __attribute__((ext_vector_type(4)));

__device__ __forceinline__ bf16x8 ldg8(const __hip_bfloat16* p){
  uint4 v = *reinterpret_cast<const uint4*>(p);
  return __builtin_bit_cast(bf16x8, v);
}
__device__ __forceinline__ float sigf(float x){ return 1.f/(1.f+__expf(-x)); }
__device__ __forceinline__ float tanhft(float x){ return 1.f - 2.f/(__expf(2.f*x)+1.f); }
__device__ __forceinline__ unsigned char f2fp8(float x){
  return (unsigned char)(__builtin_amdgcn_cvt_pk_fp8_f32(x, x, 0, false) & 0xff);
}

#define BSCALE 64.f
#define ASCALE 8.f
#define DSCALE (1.f/512.f)

// lgkm-only barrier: LDS producers drained, s_barrier, NO vmcnt(0) drain
#define BAR_LGKM() do {                                        \
  __builtin_amdgcn_sched_barrier(0);                           \
  asm volatile("s_waitcnt lgkmcnt(0)" ::: "memory");           \
  __builtin_amdgcn_s_barrier();                                \
  __builtin_amdgcn_sched_barrier(0);                           \
} while(0)

// intra-wave LDS fence
#define FENCE_LGKM() do {                                      \
  __builtin_amdgcn_sched_barrier(0);                           \
  asm volatile("s_waitcnt lgkmcnt(0)" ::: "memory");           \
  __builtin_amdgcn_sched_barrier(0);                           \
} while(0)

// ================= prep 1: W_comb[2048][16] = W_ih[:, :512] · Wcat, + folded x-bias ===========
__global__ void k_fold(const float* __restrict__ W_ih,
                       const float* __restrict__ W_cmd, const float* __restrict__ b_cmd,
                       const float* __restrict__ W_coord, const float* __restrict__ b_coord,
                       const float* __restrict__ W_head, const float* __restrict__ b_head,
                       float* __restrict__ W_comb, float* __restrict__ b_fold)
{
  const int g = blockIdx.x;      // 2048
  const int lane = threadIdx.x;  // 64
  float p[17];
  #pragma unroll
  for (int k=0;k<17;++k) p[k]=0.f;
  for (int d = lane; d < DM; d += 64){
    float w = W_ih[g*640 + d];
    #pragma unroll
    for (int c=0;c<6;++c)  p[c]    += w * W_cmd[d*6+c];
    #pragma unroll
    for (int c=0;c<8;++c)  p[6+c]  += w * W_coord[d*8+c];
    p[14] += w * W_head[d*2+0];
    p[15] += w * W_head[d*2+1];
    p[16] += w * (b_cmd[d] + b_coord[d] + b_head[d]);
  }
  #pragma unroll
  for (int k=0;k<17;++k){
    #pragma unroll
    for (int off=32; off>0; off>>=1) p[k] += __shfl_xor(p[k], off);
  }
  if (lane == 0){
    #pragma unroll
    for (int k=0;k<16;++k) W_comb[g*16+k] = p[k];
    b_fold[g] = p[16];
  }
}

// ================= prep 2: gate-B fp8, scaled xBSCALE, fragment-linear ======================
__global__ void k_bp(const float* __restrict__ Whh, const float* __restrict__ W_comb,
                     unsigned char* __restrict__ Bp)
{
  const int flat = blockIdx.x*256 + threadIdx.x;   // 1280 blocks -> 327680
  const int j   = flat & 7;
  const int l   = (flat >> 3) & 63;
  const int idx = flat >> 9;                        // n*5 + kc
  const int n   = idx / 5;
  const int kc  = idx - n*5;
  const int g   = n*16 + (l & 15);
  const int k   = kc*32 + ((l >> 4) & 3)*8 + j;
  float v = (k < 128) ? Whh[g*PR + k] : ((k < 144) ? W_comb[g*16 + (k-128)] : 0.f);
  Bp[flat] = f2fp8(BSCALE * v);
}

// ================= prep 3: W_hr bf16 fragment-linear (8 tiles) ==============================
__global__ void k_wr2(const float* __restrict__ Whr, __hip_bfloat16* __restrict__ Wr2)
{
  const int flat = blockIdx.x*256 + threadIdx.x;   // 256 blocks: 8*16*64*8 = 65536
  const int j   = flat & 7;
  const int l   = (flat >> 3) & 63;
  const int kc  = (flat >> 9) & 15;
  const int tn  = flat >> 13;                       // 0..7
  const int row = tn*16 + (l & 15);                 // p < 128
  const int d   = kc*32 + ((l >> 4) & 3)*8 + j;
  Wr2[flat] = __float2bfloat16(Whr[row*DM + d]);
}

// ================= prep 4: Wh2[t][p] frag-linear: t<14 = ln_g*Wo~; t==14 = 1 (Σh col) ======
__global__ void k_wh2(const float* __restrict__ ln_g, const float* __restrict__ ln_b,
                      const float* __restrict__ Wocmd, const float* __restrict__ Wocoord,
                      const float* __restrict__ bocmd, const float* __restrict__ bocoord,
                      __hip_bfloat16* __restrict__ Wh2, float* __restrict__ S12)
{
  if (blockIdx.x == 8){
    const int t = threadIdx.x;
    if (t >= 14) return;
    float s1 = 0.f, s2 = 0.f;
    for (int p=0; p<PR; ++p){
      float wo;
      if (t < 6) wo = Wocmd[t*PR + p];
      else {
        wo = Wocoord[(t-6)*134 + p];
        for (int k=0;k<6;++k) wo += Wocoord[(t-6)*134 + 128 + k]*Wocmd[k*PR + p];
      }
      s1 += ln_g[p]*wo;
      s2 += ln_b[p]*wo;
    }
    if (t < 6) s2 += bocmd[t];
    else {
      s2 += bocoord[t-6];
      for (int k=0;k<6;++k) s2 += Wocoord[(t-6)*134 + 128 + k]*bocmd[k];
    }
    S12[t] = s1; S12[16+t] = s2;
    return;
  }
  const int flat = blockIdx.x*256 + threadIdx.x;   // 0..2047
  const int j  = flat & 7;
  const int l  = (flat >> 3) & 63;
  const int kc = flat >> 9;                         // 0..3
  const int t  = l & 15;
  const int p  = kc*32 + ((l >> 4) & 3)*8 + j;
  float v = 0.f;
  if (t < 6) v = Wocmd[t*PR + p];
  else if (t < 14){
    v = Wocoord[(t-6)*134 + p];
    for (int k=0;k<6;++k) v += Wocoord[(t-6)*134 + 128 + k]*Wocmd[k*PR + p];
  }
  else if (t == 14) v = 1.0f;                       // Σh column
  Wh2[flat] = __float2bfloat16(t == 14 ? v : ln_g[p] * v);
}

// ================= prep 5: ctxB[b][g] = b_ih+b_hh+b_fold + ctx[b]·W_ih[g,512:] (b-major) ====
__global__ void k_ctx(const float* __restrict__ context, const float* __restrict__ W_ih,
                      const float* __restrict__ b_ih, const float* __restrict__ b_hh,
                      const float* __restrict__ b_fold, float* __restrict__ ctxB)
{
  const int idx = blockIdx.x*256 + threadIdx.x;   // 2048 blocks * 256 = B_*G4
  const int b = idx >> 11;
  const int g = idx & 2047;
  float a = b_ih[g] + b_hh[g] + b_fold[g];
  const float4* cp = reinterpret_cast<const float4*>(context + b*LAT);
  const float4* wp = reinterpret_cast<const float4*>(W_ih + g*640 + DM);
  #pragma unroll 8
  for (int q=0; q<LAT/4; ++q){
    float4 c = cp[q], w = wp[q];
    a += c.x*w.x + c.y*w.y + c.z*w.z + c.w*w.w;
  }
  ctxB[idx] = a;   // [b][g]
}

// ==== fused MFMA LSTM scan: NB=1 (256 blocks), zero-row aliasing, all-wave redundant heads ==
__global__ __launch_bounds__(512, 2)
void k_scan(const float* __restrict__ x_std,
            const float* __restrict__ ctxB,
            const unsigned char* __restrict__ Bp,
            const __hip_bfloat16* __restrict__ Wr2,
            const __hip_bfloat16* __restrict__ Wh2,
            const float* __restrict__ S12,
            float* __restrict__ out_cmd, float* __restrict__ out_coord)
{
  const int tid = threadIdx.x;
  const int w   = tid >> 6;        // wave 0..7
  const int l   = tid & 63;
  const int l15 = l & 15;
  const int lq  = l >> 4;          // 0..3
  const int b0  = blockIdx.x * NB;
  const int rz  = (l15 < NB) ? l15 : NB;   // zero-row alias: rows >= NB broadcast row NB (zero)

  __shared__ __align__(16) __hip_bfloat16 Wr2L[8*6*64*8];   // 48 KB: Wr2 kc 10..15 per wave
  __shared__ __align__(8)  unsigned char  Bwp[128*32*8];    // 32 KB: kc4 packed (real half)
  __shared__ __align__(16) float Graw[G4*NB];               // 8 KB: raw gate sums [g]
  __shared__ __align__(16) __hip_bfloat16 HF[16*520];       // row 0 real, rest zero
  __shared__ __align__(16) __hip_bfloat16 Wh2L[4*64*8];     // 4 KB: head B-frags
  __shared__ __align__(8)  unsigned char  A8[16*168];       // row 0 real, rest zero
  __shared__ __align__(16) __hip_bfloat16 HN[16*136];       // row 0 real, rest zero

  // ---- gate weights kc=0..3 -> 128 regs (AGPR) ----
  long bp[4][4][4];
  {
    const long* Bpl = reinterpret_cast<const long*>(Bp);
    #pragma unroll
    for (int dtl=0; dtl<4; ++dtl)
      #pragma unroll
      for (int gt=0; gt<4; ++gt)
        #pragma unroll
        for (int kc=0; kc<4; ++kc){
          const int n = gt*32 + w*4 + dtl;
          bp[dtl][gt][kc] = Bpl[(n*5 + kc)*64 + l];
        }
  }
  // ---- Wr2 kc 0..9 -> 40 VGPRs ----
  uint4 wrr[10];
  {
    const uint4* Wr2u4 = reinterpret_cast<const uint4*>(Wr2);
    #pragma unroll
    for (int kk=0; kk<10; ++kk)
      wrr[kk] = Wr2u4[(w*16 + kk)*64 + l];
  }
  // ---- stage Wr2 kc 10..15 -> LDS (3072 uint4) ----
  {
    const uint4* Wr2u4 = reinterpret_cast<const uint4*>(Wr2);
    uint4* dst = reinterpret_cast<uint4*>(Wr2L);
    for (int i = tid; i < 3072; i += 512){
      const int wi = i / 384;
      const int kk = (i - wi*384) >> 6;
      const int ll = i & 63;
      dst[i] = Wr2u4[(wi*16 + 10 + kk)*64 + ll];
    }
  }
  // ---- stage kc4 packed -> LDS (real half: orig lanes 0..31) ----
  {
    const long* Bpl = reinterpret_cast<const long*>(Bp);
    long* dst = reinterpret_cast<long*>(Bwp);
    for (int i = tid; i < 4096; i += 512)
      dst[i] = Bpl[((i>>5)*5 + 4)*64 + (i & 31)];
  }
  // ---- stage Wh2 -> LDS (256 uint4) ----
  {
    const uint4* src = reinterpret_cast<const uint4*>(Wh2);
    uint4* dst = reinterpret_cast<uint4*>(Wh2L);
    for (int i = tid; i < 256; i += 512) dst[i] = src[i];
  }
  // ---- ctx -> regs (step-invariant; thread owns d = tid) ----
  float cx[4];
  #pragma unroll
  for (int gt=0; gt<4; ++gt)
    cx[gt] = ctxB[b0*G4 + gt*512 + tid];

  // ---- S1/S2 for head lanes ----
  float S1k = 0.f, S2k = 0.f;
  if (l15 < 14){ S1k = S12[l15]; S2k = S12[16 + l15]; }

  // ---- zero LDS state (rows NB..15 stay zero forever) ----
  for (int i = tid; i < 16*520/2; i += 512) reinterpret_cast<unsigned*>(HF)[i] = 0u;
  for (int i = tid; i < 16*168/4; i += 512) reinterpret_cast<unsigned*>(A8)[i] = 0u;
  for (int i = tid; i < 16*136/2; i += 512) reinterpret_cast<unsigned*>(HN)[i] = 0u;
  __syncthreads();
  if (tid < NB*16){
    A8[128 + tid] = f2fp8(ASCALE * x_std[b0*S_*16 + tid]);   // x at s=0 (batch row 0)
  }

  float c_st = 0.f;   // cell state: thread owns dim d = tid
  __syncthreads();

  const f32x4 zz = {0.f, 0.f, 0.f, 0.f};
  const int a_off  = rz*168 + lq*8;        // broadcast-aliased A8 read base
  const int hf_off = rz*520 + lq*8;        // broadcast-aliased HF read base
  const int hn_off = rz*136 + lq*8;        // broadcast-aliased HN read base
  const long* Bwpl = reinterpret_cast<const long*>(Bwp);

  for (int s = 0; s < S_; ++s){
    // ---- x(s+1): ISSUE EARLY (consumed post-Bar2 -> HBM latency hidden) ----
    float xv = 0.f;
    if (s+1 < S_ && tid < NB*16) xv = x_std[(b0*S_ + s+1)*16 + tid];

    // ==== heads + LN moments for step s-1: ALL waves compute (no skew), wave 7 stores ====
    if (s > 0){
      f32x4 hd = zz, ss = zz;
      #pragma unroll
      for (int kc=0;kc<4;++kc){
        bf16x8 ha = ldg8(&HN[hn_off + kc*32]);
        bf16x8 hb = ldg8(&Wh2L[(kc*64 + l)*8]);
        hd = __builtin_amdgcn_mfma_f32_16x16x32_bf16(ha, hb, hd, 0,0,0);
        ss = __builtin_amdgcn_mfma_f32_16x16x32_bf16(ha, ha, ss, 0,0,0);
      }
      const float sh = __shfl(hd[0], 14);          // Σh   (col 14 = ones)
      const float s2 = __shfl(ss[0], 0);           // Σh²  (diag, row 0)
      const float m  = sh * (1.f/128.f);
      const float vr = s2 * (1.f/128.f) - m*m;
      const float rs = rsqrtf(vr + 1e-5f);
      if (w == 7 && lq == 0){
        const float v = rs*(hd[0] - m*S1k) + S2k;
        if (l15 < 6)       out_cmd[(b0*S_ + (s-1))*6 + l15] = v;
        else if (l15 < 14) out_coord[(b0*S_ + (s-1))*8 + (l15-6)] = v;
      }
    }

    // ======== Phase G: raw gates = A8·B (fp8 MFMA, weights on-CU) -> Graw ========
    long afr[5];
    #pragma unroll
    for (int kc=0;kc<5;++kc)
      afr[kc] = *reinterpret_cast<const long*>(&A8[a_off + kc*32]);

    #pragma unroll
    for (int dtl=0; dtl<4; ++dtl){
      const int dt = w*4 + dtl;
      long bl[4];
      #pragma unroll
      for (int gt=0; gt<4; ++gt){
        const long t0 = Bwpl[(gt*32 + dt)*32 + (l & 31)];
        bl[gt] = (lq < 2) ? t0 : 0L;
      }
      f32x4 az[4] = {zz, zz, zz, zz};
      #pragma unroll
      for (int kc=0;kc<4;++kc)
        #pragma unroll
        for (int gt=0; gt<4; ++gt)
          az[gt] = __builtin_amdgcn_mfma_f32_16x16x32_fp8_fp8(afr[kc], bp[dtl][gt][kc], az[gt], 0,0,0);
      #pragma unroll
      for (int gt=0; gt<4; ++gt)
        az[gt] = __builtin_amdgcn_mfma_f32_16x16x32_fp8_fp8(afr[4], bl[gt], az[gt], 0,0,0);
      if (lq == 0){
        #pragma unroll
        for (int gt=0; gt<4; ++gt)
          Graw[gt*512 + dt*16 + l15] = az[gt][0];
      }
    }
    // G -> A is INTRA-WAVE: no barrier needed
    FENCE_LGKM();

    // ======== Phase A: activations distributed (thread owns d = tid, 1 batch) ========
    {
      const int d = tid;
      const float iv = sigf  (Graw[0*512 + d]*DSCALE + cx[0]);
      const float fv = sigf  (Graw[1*512 + d]*DSCALE + cx[1]);
      const float gg = tanhft(Graw[2*512 + d]*DSCALE + cx[2]);
      const float ov = sigf  (Graw[3*512 + d]*DSCALE + cx[3]);
      const float cc = fv*c_st + iv*gg;
      c_st = cc;
      HF[d] = __float2bfloat16(ov*tanhft(cc));
    }
    BAR_LGKM();  // Bar2: HF ready (cross-wave); no vmcnt drain

    // ======== Phase R: h = h_full · W_hr^T (zero rows broadcast-aliased) ========
    if (s+1 < S_ && tid < NB*16)
      A8[128 + tid] = f2fp8(ASCALE * xv);

    f32x4 aA = zz, aB = zz;
    #pragma unroll
    for (int kk=0; kk<16; ++kk){
      bf16x8 a2 = ldg8(&HF[hf_off + kk*32]);
      bf16x8 b2;
      if (kk < 10) b2 = __builtin_bit_cast(bf16x8, wrr[kk]);
      else         b2 = ldg8(&Wr2L[((w*6 + (kk-10))*64 + l)*8]);
      if (kk & 1) aB = __builtin_amdgcn_mfma_f32_16x16x32_bf16(a2, b2, aB, 0,0,0);
      else        aA = __builtin_amdgcn_mfma_f32_16x16x32_bf16(a2, b2, aA, 0,0,0);
    }
    f32x4 acc2 = aA + aB;    // row 0 (lq==0) = batch, col p = w*16+l15

    // raw h -> A8 (fp8 recurrent state) and HN (bf16 for heads/LN moments)
    if (lq == 0){
      const float h = acc2[0];
      HN[w*16 + l15] = __float2bfloat16(h);
      A8[w*16 + l15] = f2fp8(ASCALE * h);
    }
    BAR_LGKM();  // Bar3: A8/HN ready for next step (cross-wave); no vmcnt drain
  }

  // ======== epilogue: heads for s = S_-1 (wave 7) ========
  if (w == 7){
    f32x4 hd = zz, ss = zz;
    #pragma unroll
    for (int kc=0;kc<4;++kc){
      bf16x8 ha = ldg8(&HN[hn_off + kc*32]);
      bf16x8 hb = ldg8(&Wh2L[(kc*64 + l)*8]);
      hd = __builtin_amdgcn_mfma_f32_16x16x32_bf16(ha, hb, hd, 0,0,0);
      ss = __builtin_amdgcn_mfma_f32_16x16x32_bf16(ha, ha, ss, 0,0,0);
    }
    const float sh = __shfl(hd[0], 14);
    const float s2 = __shfl(ss[0], 0);
    const float m  = sh * (1.f/128.f);
    const float vr = s2 * (1.f/128.f) - m*m;
    const float rs = rsqrtf(vr + 1e-5f);
    if (lq == 0){
      const float v = rs*(hd[0] - m*S1k) + S2k;
      if (l15 < 6)       out_cmd[(b0*S_ + (S_-1))*6 + l15] = v;
      else if (l15 < 14) out_coord[(b0*S_ + (S_-1))*8 + (l15-6)] = v;
    }
  }
}

extern "C" void kernel_launch(void* const* d_in, const int* in_sizes, int n_in,
                              void* d_out, int out_size, void* d_ws, size_t ws_size,
                              hipStream_t stream)
{
  const float* x_std       = (const float*)d_in[0];
  const float* context     = (const float*)d_in[1];
  const float* W_cmd       = (const float*)d_in[2];
  const float* b_cmd       = (const float*)d_in[3];
  const float* W_coord     = (const float*)d_in[4];
  const float* b_coord     = (const float*)d_in[5];
  const float* W_head      = (const float*)d_in[6];
  const float* b_head      = (const float*)d_in[7];
  const float* W_ih        = (const float*)d_in[8];
  const float* W_hh        = (const float*)d_in[9];
  const float* W_hr        = (const float*)d_in[10];
  const float* b_ih        = (const float*)d_in[11];
  const float* b_hh        = (const float*)d_in[12];
  const float* ln_g        = (const float*)d_in[13];
  const float* ln_b        = (const float*)d_in[14];
  const float* W_out_cmd   = (const float*)d_in[15];
  const float* b_out_cmd   = (const float*)d_in[16];
  const float* W_out_coord = (const float*)d_in[17];
  const float* b_out_coord = (const float*)d_in[18];

  float* out = (float*)d_out;
  char*  ws  = (char*)d_ws;

  unsigned char*  Bp   = (unsigned char*)(ws);              // 327680
  __hip_bfloat16* Wr2  = (__hip_bfloat16*)(ws + 327680);    // 131072 -> 458752
  __hip_bfloat16* Wh2  = (__hip_bfloat16*)(ws + 458752);    // 4096   -> 462848
  float* S12           = (float*)(ws + 462848);             // 128    -> 462976
  float* b_fold        = (float*)(ws + 462976);             // 8192   -> 471168
  float* W_comb        = (float*)(ws + 471168);             // 131072 -> 602240 (dead after k_bp)
  float* ctxB          = (float*)(ws + 602240);             // 2097152 -> 2699392 total

  k_fold<<<dim3(G4), dim3(64), 0, stream>>>(W_ih, W_cmd, b_cmd, W_coord, b_coord,
                                            W_head, b_head, W_comb, b_fold);
  k_bp<<<dim3(1280), dim3(256), 0, stream>>>(W_hh, W_comb, Bp);
  k_wr2<<<dim3(256), dim3(256), 0, stream>>>(W_hr, Wr2);
  k_wh2<<<dim3(9), dim3(256), 0, stream>>>(ln_g, ln_b, W_out_cmd, W_out_coord,
                                           b_out_cmd, b_out_coord, Wh2, S12);
  k_ctx<<<dim3((B_*G4)/256), dim3(256), 0, stream>>>(context, W_ih, b_ih, b_hh,
                                                     b_fold, ctxB);
  k_scan<<<dim3(B_/NB), dim3(512), 0, stream>>>(x_std, ctxB, Bp, Wr2, Wh2, S12,
                                                out, out + B_*S_*6);
}

// Round 14
// 625.880 us; speedup vs baseline: 3.4507x; 1.1538x over previous
//
#include <hip/hip_runtime.h>
#include <hip/hip_bf16.h>
#include <stdint.h>

#define B_   256
#define S_   256
#define DM   512
#define G4   2048
#define LAT  128
#define PR   128
#define NB   1      // batches per block -> 256 blocks

typedef __bf16 bf16x8 __attribute__((ext_vector_type(8)));
typedef float  f32x4  __attribute__((ext_vector_type(4)));
typedef int    i32x8  __attribute__((ext_vector_type(8)));

__device__ __forceinline__ bf16x8 ldg8(const __hip_bfloat16* p){
  uint4 v = *reinterpret_cast<const uint4*>(p);
  return __builtin_bit_cast(bf16x8, v);
}
__device__ __forceinline__ float sigf(float x){ return 1.f/(1.f+__expf(-x)); }
__device__ __forceinline__ float tanhft(float x){ return 1.f - 2.f/(__expf(2.f*x)+1.f); }
__device__ __forceinline__ unsigned char f2fp8(float x){
  return (unsigned char)(__builtin_amdgcn_cvt_pk_fp8_f32(x, x, 0, false) & 0xff);
}

#define BSCALE 64.f
#define ASCALE 8.f
#define DSCALE (1.f/512.f)
#define SCL1   0x7F7F7F7F   // e8m0 = 127 -> scale 1.0 in every byte

// lgkm-only barrier: LDS producers drained, s_barrier, NO vmcnt(0) drain
#define BAR_LGKM() do {                                        \
  __builtin_amdgcn_sched_barrier(0);                           \
  asm volatile("s_waitcnt lgkmcnt(0)" ::: "memory");           \
  __builtin_amdgcn_s_barrier();                                \
  __builtin_amdgcn_sched_barrier(0);                           \
} while(0)

// intra-wave LDS fence
#define FENCE_LGKM() do {                                      \
  __builtin_amdgcn_sched_barrier(0);                           \
  asm volatile("s_waitcnt lgkmcnt(0)" ::: "memory");           \
  __builtin_amdgcn_sched_barrier(0);                           \
} while(0)

// ================= prep 1: W_comb[2048][16] = W_ih[:, :512] · Wcat, + folded x-bias ===========
__global__ void k_fold(const float* __restrict__ W_ih,
                       const float* __restrict__ W_cmd, const float* __restrict__ b_cmd,
                       const float* __restrict__ W_coord, const float* __restrict__ b_coord,
                       const float* __restrict__ W_head, const float* __restrict__ b_head,
                       float* __restrict__ W_comb, float* __restrict__ b_fold)
{
  const int g = blockIdx.x;      // 2048
  const int lane = threadIdx.x;  // 64
  float p[17];
  #pragma unroll
  for (int k=0;k<17;++k) p[k]=0.f;
  for (int d = lane; d < DM; d += 64){
    float w = W_ih[g*640 + d];
    #pragma unroll
    for (int c=0;c<6;++c)  p[c]    += w * W_cmd[d*6+c];
    #pragma unroll
    for (int c=0;c<8;++c)  p[6+c]  += w * W_coord[d*8+c];
    p[14] += w * W_head[d*2+0];
    p[15] += w * W_head[d*2+1];
    p[16] += w * (b_cmd[d] + b_coord[d] + b_head[d]);
  }
  #pragma unroll
  for (int k=0;k<17;++k){
    #pragma unroll
    for (int off=32; off>0; off>>=1) p[k] += __shfl_xor(p[k], off);
  }
  if (lane == 0){
    #pragma unroll
    for (int k=0;k<16;++k) W_comb[g*16+k] = p[k];
    b_fold[g] = p[16];
  }
}

// ====== prep 2: gate-B fp8 in TWO layouts ======
// Bp_s: K=128 scaled-MFMA fragments: [((n*64 + l)*32 + j] = fp8(BSCALE*Whh[g][k]),
//        g = n*16 + (l&15), k = (l>>4)*32 + j (j=0..31)  -> 262144 B
// Bp4 : K-tail (k=128..143 real) packed 32-lane: [(n*32 + lp)*8 + j],
//        g = n*16 + (lp&15), k = 128 + (lp>>4)*8 + j     -> 32768 B
__global__ void k_bp(const float* __restrict__ Whh, const float* __restrict__ W_comb,
                     unsigned char* __restrict__ Bp_s, unsigned char* __restrict__ Bp4)
{
  if (blockIdx.x < 1024){
    const int flat = blockIdx.x*256 + threadIdx.x;   // 0..262143
    const int j = flat & 31;
    const int l = (flat >> 5) & 63;
    const int n = flat >> 11;
    const int g = n*16 + (l & 15);
    const int k = ((l >> 4) & 3)*32 + j;             // 0..127
    Bp_s[flat] = f2fp8(BSCALE * Whh[g*PR + k]);
  } else {
    const int flat = (blockIdx.x - 1024)*256 + threadIdx.x;  // 0..32767
    const int j  = flat & 7;
    const int lp = (flat >> 3) & 31;
    const int n  = flat >> 8;
    const int g  = n*16 + (lp & 15);
    const int k  = 128 + (lp >> 4)*8 + j;            // 128..143
    Bp4[flat] = f2fp8(BSCALE * W_comb[g*16 + (k - 128)]);
  }
}

// ================= prep 3: W_hr bf16 fragment-linear (8 tiles) ==============================
__global__ void k_wr2(const float* __restrict__ Whr, __hip_bfloat16* __restrict__ Wr2)
{
  const int flat = blockIdx.x*256 + threadIdx.x;   // 256 blocks: 8*16*64*8 = 65536
  const int j   = flat & 7;
  const int l   = (flat >> 3) & 63;
  const int kc  = (flat >> 9) & 15;
  const int tn  = flat >> 13;                       // 0..7
  const int row = tn*16 + (l & 15);                 // p < 128
  const int d   = kc*32 + ((l >> 4) & 3)*8 + j;
  Wr2[flat] = __float2bfloat16(Whr[row*DM + d]);
}

// ================= prep 4: Wh2[t][p] frag-linear: t<14 = ln_g*Wo~; t==14 = 1 (Σh col) ======
__global__ void k_wh2(const float* __restrict__ ln_g, const float* __restrict__ ln_b,
                      const float* __restrict__ Wocmd, const float* __restrict__ Wocoord,
                      const float* __restrict__ bocmd, const float* __restrict__ bocoord,
                      __hip_bfloat16* __restrict__ Wh2, float* __restrict__ S12)
{
  if (blockIdx.x == 8){
    const int t = threadIdx.x;
    if (t >= 14) return;
    float s1 = 0.f, s2 = 0.f;
    for (int p=0; p<PR; ++p){
      float wo;
      if (t < 6) wo = Wocmd[t*PR + p];
      else {
        wo = Wocoord[(t-6)*134 + p];
        for (int k=0;k<6;++k) wo += Wocoord[(t-6)*134 + 128 + k]*Wocmd[k*PR + p];
      }
      s1 += ln_g[p]*wo;
      s2 += ln_b[p]*wo;
    }
    if (t < 6) s2 += bocmd[t];
    else {
      s2 += bocoord[t-6];
      for (int k=0;k<6;++k) s2 += Wocoord[(t-6)*134 + 128 + k]*bocmd[k];
    }
    S12[t] = s1; S12[16+t] = s2;
    return;
  }
  const int flat = blockIdx.x*256 + threadIdx.x;   // 0..2047
  const int j  = flat & 7;
  const int l  = (flat >> 3) & 63;
  const int kc = flat >> 9;                         // 0..3
  const int t  = l & 15;
  const int p  = kc*32 + ((l >> 4) & 3)*8 + j;
  float v = 0.f;
  if (t < 6) v = Wocmd[t*PR + p];
  else if (t < 14){
    v = Wocoord[(t-6)*134 + p];
    for (int k=0;k<6;++k) v += Wocoord[(t-6)*134 + 128 + k]*Wocmd[k*PR + p];
  }
  else if (t == 14) v = 1.0f;                       // Σh column
  Wh2[flat] = __float2bfloat16(t == 14 ? v : ln_g[p] * v);
}

// ================= prep 5: ctxB[b][g] = b_ih+b_hh+b_fold + ctx[b]·W_ih[g,512:] (b-major) ====
__global__ void k_ctx(const float* __restrict__ context, const float* __restrict__ W_ih,
                      const float* __restrict__ b_ih, const float* __restrict__ b_hh,
                      const float* __restrict__ b_fold, float* __restrict__ ctxB)
{
  const int idx = blockIdx.x*256 + threadIdx.x;   // 2048 blocks * 256 = B_*G4
  const int b = idx >> 11;
  const int g = idx & 2047;
  float a = b_ih[g] + b_hh[g] + b_fold[g];
  const float4* cp = reinterpret_cast<const float4*>(context + b*LAT);
  const float4* wp = reinterpret_cast<const float4*>(W_ih + g*640 + DM);
  #pragma unroll 8
  for (int q=0; q<LAT/4; ++q){
    float4 c = cp[q], w = wp[q];
    a += c.x*w.x + c.y*w.y + c.z*w.z + c.w*w.w;
  }
  ctxB[idx] = a;   // [b][g]
}

// ==== fused MFMA LSTM scan: K=128 scaled MFMA for gates, NB=1, zero-row aliasing ============
__global__ __launch_bounds__(512, 2)
void k_scan(const float* __restrict__ x_std,
            const float* __restrict__ ctxB,
            const unsigned char* __restrict__ Bp_s,
            const unsigned char* __restrict__ Bp4,
            const __hip_bfloat16* __restrict__ Wr2,
            const __hip_bfloat16* __restrict__ Wh2,
            const float* __restrict__ S12,
            float* __restrict__ out_cmd, float* __restrict__ out_coord)
{
  const int tid = threadIdx.x;
  const int w   = tid >> 6;        // wave 0..7
  const int l   = tid & 63;
  const int l15 = l & 15;
  const int lq  = l >> 4;          // 0..3
  const int b0  = blockIdx.x * NB;
  const int rz  = (l15 < NB) ? l15 : NB;   // zero-row alias

  __shared__ __align__(16) __hip_bfloat16 Wr2L[8*6*64*8];   // 48 KB: Wr2 kc 10..15 per wave
  __shared__ __align__(8)  unsigned char  Bwp[128*32*8];    // 32 KB: K-tail packed
  __shared__ __align__(16) float Graw[G4*NB];               // 8 KB: raw gate sums [g]
  __shared__ __align__(16) __hip_bfloat16 HF[16*520];       // row 0 real, rest zero
  __shared__ __align__(16) __hip_bfloat16 Wh2L[4*64*8];     // 4 KB: head B-frags
  __shared__ __align__(16) unsigned char  A8[16*176];       // row 0 real (stride 176, 16-aligned)
  __shared__ __align__(16) __hip_bfloat16 HN[16*136];       // row 0 real, rest zero

  // ---- gate weights K=0..127 -> 128 regs (AGPR), scaled-MFMA v8i32 fragments ----
  i32x8 bp[4][4];
  #pragma unroll
  for (int dtl=0; dtl<4; ++dtl)
    #pragma unroll
    for (int gt=0; gt<4; ++gt){
      const int n = gt*32 + w*4 + dtl;
      bp[dtl][gt] = *reinterpret_cast<const i32x8*>(Bp_s + (n*64 + l)*32);
    }
  // ---- Wr2 kc 0..9 -> 40 VGPRs ----
  uint4 wrr[10];
  {
    const uint4* Wr2u4 = reinterpret_cast<const uint4*>(Wr2);
    #pragma unroll
    for (int kk=0; kk<10; ++kk)
      wrr[kk] = Wr2u4[(w*16 + kk)*64 + l];
  }
  // ---- stage Wr2 kc 10..15 -> LDS (3072 uint4) ----
  {
    const uint4* Wr2u4 = reinterpret_cast<const uint4*>(Wr2);
    uint4* dst = reinterpret_cast<uint4*>(Wr2L);
    for (int i = tid; i < 3072; i += 512){
      const int wi = i / 384;
      const int kk = (i - wi*384) >> 6;
      const int ll = i & 63;
      dst[i] = Wr2u4[(wi*16 + 10 + kk)*64 + ll];
    }
  }
  // ---- stage K-tail packed -> LDS (4096 longs) ----
  {
    const long* src = reinterpret_cast<const long*>(Bp4);
    long* dst = reinterpret_cast<long*>(Bwp);
    for (int i = tid; i < 4096; i += 512) dst[i] = src[i];
  }
  // ---- stage Wh2 -> LDS (256 uint4) ----
  {
    const uint4* src = reinterpret_cast<const uint4*>(Wh2);
    uint4* dst = reinterpret_cast<uint4*>(Wh2L);
    for (int i = tid; i < 256; i += 512) dst[i] = src[i];
  }
  // ---- ctx -> regs (step-invariant; thread owns d = tid) ----
  float cx[4];
  #pragma unroll
  for (int gt=0; gt<4; ++gt)
    cx[gt] = ctxB[b0*G4 + gt*512 + tid];

  // ---- S1/S2 for head lanes ----
  float S1k = 0.f, S2k = 0.f;
  if (l15 < 14){ S1k = S12[l15]; S2k = S12[16 + l15]; }

  // ---- zero LDS state (rows NB..15 stay zero forever) ----
  for (int i = tid; i < 16*520/2; i += 512) reinterpret_cast<unsigned*>(HF)[i] = 0u;
  for (int i = tid; i < 16*176/4; i += 512) reinterpret_cast<unsigned*>(A8)[i] = 0u;
  for (int i = tid; i < 16*136/2; i += 512) reinterpret_cast<unsigned*>(HN)[i] = 0u;
  __syncthreads();
  if (tid < NB*16){
    A8[128 + tid] = f2fp8(ASCALE * x_std[b0*S_*16 + tid]);   // x at s=0 (row 0)
  }

  float c_st = 0.f;   // cell state: thread owns dim d = tid
  __syncthreads();

  const f32x4 zz = {0.f, 0.f, 0.f, 0.f};
  const int aS_off = rz*176 + lq*32;        // scaled A-frag: k = lq*32 .. +31
  const int a4_off = rz*176 + 128 + lq*8;   // K-tail A-frag
  const int hf_off = rz*520 + lq*8;
  const int hn_off = rz*136 + lq*8;
  const long* Bwpl = reinterpret_cast<const long*>(Bwp);

  for (int s = 0; s < S_; ++s){
    // ---- x(s+1): ISSUE EARLY (consumed post-Bar2 -> HBM latency hidden) ----
    float xv = 0.f;
    if (s+1 < S_ && tid < NB*16) xv = x_std[(b0*S_ + s+1)*16 + tid];

    // ==== heads + LN moments for step s-1: ALL waves compute (no skew), wave 7 stores ====
    if (s > 0){
      f32x4 hd = zz, ss = zz;
      #pragma unroll
      for (int kc=0;kc<4;++kc){
        bf16x8 ha = ldg8(&HN[hn_off + kc*32]);
        bf16x8 hb = ldg8(&Wh2L[(kc*64 + l)*8]);
        hd = __builtin_amdgcn_mfma_f32_16x16x32_bf16(ha, hb, hd, 0,0,0);
        ss = __builtin_amdgcn_mfma_f32_16x16x32_bf16(ha, ha, ss, 0,0,0);
      }
      const float sh = __shfl(hd[0], 14);          // Σh   (col 14 = ones)
      const float s2 = __shfl(ss[0], 0);           // Σh²  (diag, row 0)
      const float m  = sh * (1.f/128.f);
      const float vr = s2 * (1.f/128.f) - m*m;
      const float rs = rsqrtf(vr + 1e-5f);
      if (w == 7 && lq == 0){
        const float v = rs*(hd[0] - m*S1k) + S2k;
        if (l15 < 6)       out_cmd[(b0*S_ + (s-1))*6 + l15] = v;
        else if (l15 < 14) out_coord[(b0*S_ + (s-1))*8 + (l15-6)] = v;
      }
    }

    // ======== Phase G: raw gates = A8·B ; K=0..127 via ONE scaled MFMA, K-tail via fp8 ======
    i32x8 afrS = *reinterpret_cast<const i32x8*>(&A8[aS_off]);
    long  afr4 = *reinterpret_cast<const long*>(&A8[a4_off]);

    #pragma unroll
    for (int dtl=0; dtl<4; ++dtl){
      const int dt = w*4 + dtl;
      long bl[4];
      #pragma unroll
      for (int gt=0; gt<4; ++gt){
        const long t0 = Bwpl[(gt*32 + dt)*32 + (l & 31)];
        bl[gt] = (lq < 2) ? t0 : 0L;
      }
      f32x4 az[4] = {zz, zz, zz, zz};
      #pragma unroll
      for (int gt=0; gt<4; ++gt)
        az[gt] = __builtin_amdgcn_mfma_scale_f32_16x16x128_f8f6f4(
                   afrS, bp[dtl][gt], az[gt], 0, 0, 0, SCL1, 0, SCL1);
      #pragma unroll
      for (int gt=0; gt<4; ++gt)
        az[gt] = __builtin_amdgcn_mfma_f32_16x16x32_fp8_fp8(afr4, bl[gt], az[gt], 0,0,0);
      if (lq == 0){
        #pragma unroll
        for (int gt=0; gt<4; ++gt)
          Graw[gt*512 + dt*16 + l15] = az[gt][0];
      }
    }
    // G -> A is INTRA-WAVE: no barrier needed
    FENCE_LGKM();

    // ======== Phase A: activations distributed (thread owns d = tid, 1 batch) ========
    {
      const int d = tid;
      const float iv = sigf  (Graw[0*512 + d]*DSCALE + cx[0]);
      const float fv = sigf  (Graw[1*512 + d]*DSCALE + cx[1]);
      const float gg = tanhft(Graw[2*512 + d]*DSCALE + cx[2]);
      const float ov = sigf  (Graw[3*512 + d]*DSCALE + cx[3]);
      const float cc = fv*c_st + iv*gg;
      c_st = cc;
      HF[d] = __float2bfloat16(ov*tanhft(cc));
    }
    BAR_LGKM();  // Bar2: HF ready (cross-wave); no vmcnt drain

    // ======== Phase R: h = h_full · W_hr^T (zero rows broadcast-aliased) ========
    if (s+1 < S_ && tid < NB*16)
      A8[128 + tid] = f2fp8(ASCALE * xv);

    f32x4 aA = zz, aB = zz;
    #pragma unroll
    for (int kk=0; kk<16; ++kk){
      bf16x8 a2 = ldg8(&HF[hf_off + kk*32]);
      bf16x8 b2;
      if (kk < 10) b2 = __builtin_bit_cast(bf16x8, wrr[kk]);
      else         b2 = ldg8(&Wr2L[((w*6 + (kk-10))*64 + l)*8]);
      if (kk & 1) aB = __builtin_amdgcn_mfma_f32_16x16x32_bf16(a2, b2, aB, 0,0,0);
      else        aA = __builtin_amdgcn_mfma_f32_16x16x32_bf16(a2, b2, aA, 0,0,0);
    }
    f32x4 acc2 = aA + aB;    // row 0 (lq==0) = batch, col p = w*16+l15

    // raw h -> A8 (fp8 recurrent state) and HN (bf16 for heads/LN moments)
    if (lq == 0){
      const float h = acc2[0];
      HN[w*16 + l15] = __float2bfloat16(h);
      A8[w*16 + l15] = f2fp8(ASCALE * h);
    }
    BAR_LGKM();  // Bar3: A8/HN ready for next step (cross-wave); no vmcnt drain
  }

  // ======== epilogue: heads for s = S_-1 (wave 7) ========
  if (w == 7){
    f32x4 hd = zz, ss = zz;
    #pragma unroll
    for (int kc=0;kc<4;++kc){
      bf16x8 ha = ldg8(&HN[hn_off + kc*32]);
      bf16x8 hb = ldg8(&Wh2L[(kc*64 + l)*8]);
      hd = __builtin_amdgcn_mfma_f32_16x16x32_bf16(ha, hb, hd, 0,0,0);
      ss = __builtin_amdgcn_mfma_f32_16x16x32_bf16(ha, ha, ss, 0,0,0);
    }
    const float sh = __shfl(hd[0], 14);
    const float s2 = __shfl(ss[0], 0);
    const float m  = sh * (1.f/128.f);
    const float vr = s2 * (1.f/128.f) - m*m;
    const float rs = rsqrtf(vr + 1e-5f);
    if (lq == 0){
      const float v = rs*(hd[0] - m*S1k) + S2k;
      if (l15 < 6)       out_cmd[(b0*S_ + (S_-1))*6 + l15] = v;
      else if (l15 < 14) out_coord[(b0*S_ + (S_-1))*8 + (l15-6)] = v;
    }
  }
}

extern "C" void kernel_launch(void* const* d_in, const int* in_sizes, int n_in,
                              void* d_out, int out_size, void* d_ws, size_t ws_size,
                              hipStream_t stream)
{
  const float* x_std       = (const float*)d_in[0];
  const float* context     = (const float*)d_in[1];
  const float* W_cmd       = (const float*)d_in[2];
  const float* b_cmd       = (const float*)d_in[3];
  const float* W_coord     = (const float*)d_in[4];
  const float* b_coord     = (const float*)d_in[5];
  const float* W_head      = (const float*)d_in[6];
  const float* b_head      = (const float*)d_in[7];
  const float* W_ih        = (const float*)d_in[8];
  const float* W_hh        = (const float*)d_in[9];
  const float* W_hr        = (const float*)d_in[10];
  const float* b_ih        = (const float*)d_in[11];
  const float* b_hh        = (const float*)d_in[12];
  const float* ln_g        = (const float*)d_in[13];
  const float* ln_b        = (const float*)d_in[14];
  const float* W_out_cmd   = (const float*)d_in[15];
  const float* b_out_cmd   = (const float*)d_in[16];
  const float* W_out_coord = (const float*)d_in[17];
  const float* b_out_coord = (const float*)d_in[18];

  float* out = (float*)d_out;
  char*  ws  = (char*)d_ws;

  unsigned char*  Bp_s = (unsigned char*)(ws);              // 262144
  unsigned char*  Bp4  = (unsigned char*)(ws + 262144);     // 32768  -> 294912
  __hip_bfloat16* Wr2  = (__hip_bfloat16*)(ws + 294912);    // 131072 -> 425984
  __hip_bfloat16* Wh2  = (__hip_bfloat16*)(ws + 425984);    // 4096   -> 430080
  float* S12           = (float*)(ws + 430080);             // 128    -> 430208
  float* b_fold        = (float*)(ws + 430208);             // 8192   -> 438400
  float* W_comb        = (float*)(ws + 438400);             // 131072 -> 569472
  float* ctxB          = (float*)(ws + 569472);             // 2097152 -> 2666624 total

  k_fold<<<dim3(G4), dim3(64), 0, stream>>>(W_ih, W_cmd, b_cmd, W_coord, b_coord,
                                            W_head, b_head, W_comb, b_fold);
  k_bp<<<dim3(1152), dim3(256), 0, stream>>>(W_hh, W_comb, Bp_s, Bp4);
  k_wr2<<<dim3(256), dim3(256), 0, stream>>>(W_hr, Wr2);
  k_wh2<<<dim3(9), dim3(256), 0, stream>>>(ln_g, ln_b, W_out_cmd, W_out_coord,
                                           b_out_cmd, b_out_coord, Wh2, S12);
  k_ctx<<<dim3((B_*G4)/256), dim3(256), 0, stream>>>(context, W_ih, b_ih, b_hh,
                                                     b_fold, ctxB);
  k_scan<<<dim3(B_/NB), dim3(512), 0, stream>>>(x_std, ctxB, Bp_s, Bp4, Wr2, Wh2, S12,
                                                out, out + B_*S_*6);
}

// Round 16
// 573.029 us; speedup vs baseline: 3.7690x; 1.0922x over previous
//
#include <hip/hip_runtime.h>
#include <hip/hip_bf16.h>
#include <stdint.h>

#define B_   256
#define S_   256
#define DM   512
#define G4   2048
#define LAT  128
#define PR   128
#define NB   1      // batches per block -> 256 blocks

typedef __bf16 bf16x8 __attribute__((ext_vector_type(8)));
typedef float  f32x4  __attribute__((ext_vector_type(4)));
typedef int    i32x8  __attribute__((ext_vector_type(8)));

__device__ __forceinline__ bf16x8 ldg8(const __hip_bfloat16* p){
  uint4 v = *reinterpret_cast<const uint4*>(p);
  return __builtin_bit_cast(bf16x8, v);
}
__device__ __forceinline__ float rcpf(float x){ return __builtin_amdgcn_rcpf(x); }
__device__ __forceinline__ unsigned char f2fp8(float x){
  return (unsigned char)(__builtin_amdgcn_cvt_pk_fp8_f32(x, x, 0, false) & 0xff);
}

#define BSCALE 64.f          // gate weights (Whh, Wcomb tail)
#define ASCALE 8.f           // h / x in A8
#define DSCALE (1.f/512.f)   // gate descale (8*64)
#define L2E    1.4426950408889634f
#define SCL1   0x7F7F7F7F    // e8m0 = 127 -> x1.0 scales

#define BAR_LGKM() do {                                        \
  __builtin_amdgcn_sched_barrier(0);                           \
  asm volatile("s_waitcnt lgkmcnt(0)" ::: "memory");           \
  __builtin_amdgcn_s_barrier();                                \
  __builtin_amdgcn_sched_barrier(0);                           \
} while(0)

#define FENCE_LGKM() do {                                      \
  __builtin_amdgcn_sched_barrier(0);                           \
  asm volatile("s_waitcnt lgkmcnt(0)" ::: "memory");           \
  __builtin_amdgcn_sched_barrier(0);                           \
} while(0)

// ================= prep 1: W_comb[2048][16] = W_ih[:, :512] · Wcat, + folded x-bias ===========
__global__ void k_fold(const float* __restrict__ W_ih,
                       const float* __restrict__ W_cmd, const float* __restrict__ b_cmd,
                       const float* __restrict__ W_coord, const float* __restrict__ b_coord,
                       const float* __restrict__ W_head, const float* __restrict__ b_head,
                       float* __restrict__ W_comb, float* __restrict__ b_fold)
{
  const int g = blockIdx.x;      // 2048
  const int lane = threadIdx.x;  // 64
  float p[17];
  #pragma unroll
  for (int k=0;k<17;++k) p[k]=0.f;
  for (int d = lane; d < DM; d += 64){
    float w = W_ih[g*640 + d];
    #pragma unroll
    for (int c=0;c<6;++c)  p[c]    += w * W_cmd[d*6+c];
    #pragma unroll
    for (int c=0;c<8;++c)  p[6+c]  += w * W_coord[d*8+c];
    p[14] += w * W_head[d*2+0];
    p[15] += w * W_head[d*2+1];
    p[16] += w * (b_cmd[d] + b_coord[d] + b_head[d]);
  }
  #pragma unroll
  for (int k=0;k<17;++k){
    #pragma unroll
    for (int off=32; off>0; off>>=1) p[k] += __shfl_xor(p[k], off);
  }
  if (lane == 0){
    #pragma unroll
    for (int k=0;k<16;++k) W_comb[g*16+k] = p[k];
    b_fold[g] = p[16];
  }
}

// ====== prep 2: gate-B fp8: Bp_s = K=128 scaled frags; Bp4 = K-tail FULL-lane (zeros baked) ==
__global__ void k_bp(const float* __restrict__ Whh, const float* __restrict__ W_comb,
                     unsigned char* __restrict__ Bp_s, unsigned char* __restrict__ Bp4)
{
  if (blockIdx.x < 1024){
    const int flat = blockIdx.x*256 + threadIdx.x;   // 0..262143
    const int j = flat & 31;
    const int l = (flat >> 5) & 63;
    const int n = flat >> 11;
    const int g = n*16 + (l & 15);
    const int k = ((l >> 4) & 3)*32 + j;             // 0..127
    Bp_s[flat] = f2fp8(BSCALE * Whh[g*PR + k]);
  } else {
    const int flat = (blockIdx.x - 1024)*256 + threadIdx.x;  // 0..65535
    const int j  = flat & 7;
    const int l  = (flat >> 3) & 63;
    const int n  = flat >> 9;                        // 0..127
    const int lq = (l >> 4) & 3;
    const int g  = n*16 + (l & 15);
    const float v = (lq < 2) ? W_comb[g*16 + lq*8 + j] : 0.f;
    Bp4[flat] = f2fp8(BSCALE * v);
  }
}

// ================= prep 3: W_hr bf16 fragment-linear (8 tiles) ==============================
__global__ void k_wr2(const float* __restrict__ Whr, __hip_bfloat16* __restrict__ Wr2)
{
  const int flat = blockIdx.x*256 + threadIdx.x;   // 256 blocks: 8*16*64*8 = 65536
  const int j   = flat & 7;
  const int l   = (flat >> 3) & 63;
  const int kc  = (flat >> 9) & 15;
  const int tn  = flat >> 13;                       // 0..7
  const int row = tn*16 + (l & 15);                 // p < 128
  const int d   = kc*32 + ((l >> 4) & 3)*8 + j;
  Wr2[flat] = __float2bfloat16(Whr[row*DM + d]);
}

// ================= prep 4: Wh2[t][p] frag-linear: t<14 = ln_g*Wo~; t==14 = 1 (Σh col) ======
__global__ void k_wh2(const float* __restrict__ ln_g, const float* __restrict__ ln_b,
                      const float* __restrict__ Wocmd, const float* __restrict__ Wocoord,
                      const float* __restrict__ bocmd, const float* __restrict__ bocoord,
                      __hip_bfloat16* __restrict__ Wh2, float* __restrict__ S12)
{
  if (blockIdx.x == 8){
    const int t = threadIdx.x;
    if (t >= 14) return;
    float s1 = 0.f, s2 = 0.f;
    for (int p=0; p<PR; ++p){
      float wo;
      if (t < 6) wo = Wocmd[t*PR + p];
      else {
        wo = Wocoord[(t-6)*134 + p];
        for (int k=0;k<6;++k) wo += Wocoord[(t-6)*134 + 128 + k]*Wocmd[k*PR + p];
      }
      s1 += ln_g[p]*wo;
      s2 += ln_b[p]*wo;
    }
    if (t < 6) s2 += bocmd[t];
    else {
      s2 += bocoord[t-6];
      for (int k=0;k<6;++k) s2 += Wocoord[(t-6)*134 + 128 + k]*bocmd[k];
    }
    S12[t] = s1; S12[16+t] = s2;
    return;
  }
  const int flat = blockIdx.x*256 + threadIdx.x;   // 0..2047
  const int j  = flat & 7;
  const int l  = (flat >> 3) & 63;
  const int kc = flat >> 9;                         // 0..3
  const int t  = l & 15;
  const int p  = kc*32 + ((l >> 4) & 3)*8 + j;
  float v = 0.f;
  if (t < 6) v = Wocmd[t*PR + p];
  else if (t < 14){
    v = Wocoord[(t-6)*134 + p];
    for (int k=0;k<6;++k) v += Wocoord[(t-6)*134 + 128 + k]*Wocmd[k*PR + p];
  }
  else if (t == 14) v = 1.0f;                       // Σh column
  Wh2[flat] = __float2bfloat16(t == 14 ? v : ln_g[p] * v);
}

// ================= prep 5: ctxB[b][g] = b_ih+b_hh+b_fold + ctx[b]·W_ih[g,512:] (b-major) ====
__global__ void k_ctx(const float* __restrict__ context, const float* __restrict__ W_ih,
                      const float* __restrict__ b_ih, const float* __restrict__ b_hh,
                      const float* __restrict__ b_fold, float* __restrict__ ctxB)
{
  const int idx = blockIdx.x*256 + threadIdx.x;   // 2048 blocks * 256 = B_*G4
  const int b = idx >> 11;
  const int g = idx & 2047;
  float a = b_ih[g] + b_hh[g] + b_fold[g];
  const float4* cp = reinterpret_cast<const float4*>(context + b*LAT);
  const float4* wp = reinterpret_cast<const float4*>(W_ih + g*640 + DM);
  #pragma unroll 8
  for (int q=0; q<LAT/4; ++q){
    float4 c = cp[q], w = wp[q];
    a += c.x*w.x + c.y*w.y + c.z*w.z + c.w*w.w;
  }
  ctxB[idx] = a;   // [b][g]
}

// ==== fused MFMA LSTM scan: K=128 scaled gates (fp8), bf16 R/heads (r14-verified) ===========
__global__ __launch_bounds__(512, 2)
void k_scan(const float* __restrict__ x_std,
            const float* __restrict__ ctxB,
            const unsigned char* __restrict__ Bp_s,
            const unsigned char* __restrict__ Bp4,
            const __hip_bfloat16* __restrict__ Wr2,
            const __hip_bfloat16* __restrict__ Wh2,
            const float* __restrict__ S12,
            float* __restrict__ out_cmd, float* __restrict__ out_coord)
{
  const int tid = threadIdx.x;
  const int w   = tid >> 6;        // wave 0..7
  const int l   = tid & 63;
  const int l15 = l & 15;
  const int lq  = l >> 4;          // 0..3
  const int b0  = blockIdx.x;
  const int rz  = (l15 < NB) ? l15 : NB;   // zero-row alias

  __shared__ __align__(16) __hip_bfloat16 Wr2L[8*6*64*8];   // 48 KB: Wr2 kc 10..15 per wave
  __shared__ __align__(8)  unsigned char  Bwp[128*64*8];    // 64 KB: K-tail B full-lane (zeros baked)
  __shared__ __align__(16) float Graw[G4*NB];               // 8 KB: raw gate sums [g]
  __shared__ __align__(16) __hip_bfloat16 HF[16*520];       // row 0 real, rest zero
  __shared__ __align__(16) __hip_bfloat16 Wh2L[4*64*8];     // 4 KB: head B-frags
  __shared__ __align__(16) unsigned char  A8[16*176];       // row 0 real (stride 176)
  __shared__ __align__(16) __hip_bfloat16 HN[16*136];       // row 0 real, rest zero

  // ---- gate weights K=0..127 -> 128 regs (AGPR), scaled-MFMA v8i32 fragments ----
  i32x8 bp[4][4];
  #pragma unroll
  for (int dtl=0; dtl<4; ++dtl)
    #pragma unroll
    for (int gt=0; gt<4; ++gt){
      const int n = gt*32 + w*4 + dtl;
      bp[dtl][gt] = *reinterpret_cast<const i32x8*>(Bp_s + (n*64 + l)*32);
    }
  // ---- Wr2 kc 0..9 -> 40 VGPRs ----
  uint4 wrr[10];
  {
    const uint4* Wr2u4 = reinterpret_cast<const uint4*>(Wr2);
    #pragma unroll
    for (int kk=0; kk<10; ++kk)
      wrr[kk] = Wr2u4[(w*16 + kk)*64 + l];
  }
  // ---- stage Wr2 kc 10..15 -> LDS (3072 uint4) ----
  {
    const uint4* Wr2u4 = reinterpret_cast<const uint4*>(Wr2);
    uint4* dst = reinterpret_cast<uint4*>(Wr2L);
    for (int i = tid; i < 3072; i += 512){
      const int wi = i / 384;
      const int kk = (i - wi*384) >> 6;
      const int ll = i & 63;
      dst[i] = Wr2u4[(wi*16 + 10 + kk)*64 + ll];
    }
  }
  // ---- stage K-tail B -> LDS (8192 longs, zeros baked for lq>=2) ----
  {
    const long* src = reinterpret_cast<const long*>(Bp4);
    long* dst = reinterpret_cast<long*>(Bwp);
    for (int i = tid; i < 8192; i += 512) dst[i] = src[i];
  }
  // ---- stage Wh2 -> LDS (256 uint4) ----
  {
    const uint4* src = reinterpret_cast<const uint4*>(Wh2);
    uint4* dst = reinterpret_cast<uint4*>(Wh2L);
    for (int i = tid; i < 256; i += 512) dst[i] = src[i];
  }
  // ---- ctx -> regs, pre-folded with log2e (gate 2 uses tanh -> 2x) ----
  float cxL[4];
  #pragma unroll
  for (int gt=0; gt<4; ++gt)
    cxL[gt] = ctxB[b0*G4 + gt*512 + tid] * (gt == 2 ? 2.f*L2E : L2E);
  const float DSC_L  = DSCALE * L2E;
  const float DSC_L2 = 2.f * DSCALE * L2E;

  // ---- S1/S2 for head lanes ----
  float S1k = 0.f, S2k = 0.f;
  if (l15 < 14){ S1k = S12[l15]; S2k = S12[16 + l15]; }

  // ---- zero LDS state (rows NB..15 stay zero forever) ----
  for (int i = tid; i < 16*520/2; i += 512) reinterpret_cast<unsigned*>(HF)[i] = 0u;
  for (int i = tid; i < 16*176/4; i += 512) reinterpret_cast<unsigned*>(A8)[i] = 0u;
  for (int i = tid; i < 16*136/2; i += 512) reinterpret_cast<unsigned*>(HN)[i] = 0u;
  __syncthreads();
  if (tid < 16)
    A8[128 + tid] = f2fp8(ASCALE * x_std[b0*S_*16 + tid]);   // x at s=0 (row 0)

  float c_st = 0.f;   // cell state: thread owns dim d = tid
  __syncthreads();

  const f32x4 zz = {0.f, 0.f, 0.f, 0.f};
  const int aS_off = rz*176 + lq*32;        // scaled A-frag: k = lq*32 .. +31
  const int a4_off = rz*176 + 128 + lq*8;   // K-tail A-frag
  const int hf_off = rz*520 + lq*8;
  const int hn_off = rz*136 + lq*8;
  const long* Bwpl = reinterpret_cast<const long*>(Bwp);

  for (int s = 0; s < S_; ++s){
    // ---- x(s+1): ISSUE EARLY (consumed post-Bar2 -> HBM latency hidden) ----
    float xv = 0.f;
    if (s+1 < S_ && tid < 16) xv = x_std[(b0*S_ + s+1)*16 + tid];

    // ==== heads + LN moments for step s-1: ALL waves compute (no skew), wave 7 stores ====
    if (s > 0){
      f32x4 hd = zz, ss = zz;
      #pragma unroll
      for (int kc=0;kc<4;++kc){
        bf16x8 ha = ldg8(&HN[hn_off + kc*32]);
        bf16x8 hb = ldg8(&Wh2L[(kc*64 + l)*8]);
        hd = __builtin_amdgcn_mfma_f32_16x16x32_bf16(ha, hb, hd, 0,0,0);
        ss = __builtin_amdgcn_mfma_f32_16x16x32_bf16(ha, ha, ss, 0,0,0);
      }
      const float sh = __shfl(hd[0], 14);          // Σh   (col 14 = ones)
      const float s2 = __shfl(ss[0], 0);           // Σh²  (diag, row 0)
      const float m  = sh * (1.f/128.f);
      const float vr = s2 * (1.f/128.f) - m*m;
      const float rs = rsqrtf(vr + 1e-5f);
      if (w == 7 && lq == 0){
        const float v = rs*(hd[0] - m*S1k) + S2k;
        if (l15 < 6)       out_cmd[(b0*S_ + (s-1))*6 + l15] = v;
        else if (l15 < 14) out_coord[(b0*S_ + (s-1))*8 + (l15-6)] = v;
      }
    }

    // ======== Phase G: raw gates = A8·B ; K=0..127 via ONE scaled MFMA, K-tail via fp8 ======
    i32x8 afrS = *reinterpret_cast<const i32x8*>(&A8[aS_off]);
    long  afr4 = *reinterpret_cast<const long*>(&A8[a4_off]);

    #pragma unroll
    for (int dtl=0; dtl<4; ++dtl){
      const int dt = w*4 + dtl;
      long bl[4];
      #pragma unroll
      for (int gt=0; gt<4; ++gt)
        bl[gt] = Bwpl[(gt*32 + dt)*64 + l];               // zeros baked for lq>=2
      f32x4 az[4] = {zz, zz, zz, zz};
      #pragma unroll
      for (int gt=0; gt<4; ++gt)
        az[gt] = __builtin_amdgcn_mfma_scale_f32_16x16x128_f8f6f4(
                   afrS, bp[dtl][gt], az[gt], 0, 0, 0, SCL1, 0, SCL1);
      #pragma unroll
      for (int gt=0; gt<4; ++gt)
        az[gt] = __builtin_amdgcn_mfma_f32_16x16x32_fp8_fp8(afr4, bl[gt], az[gt], 0,0,0);
      if (lq == 0){
        #pragma unroll
        for (int gt=0; gt<4; ++gt)
          Graw[gt*512 + dt*16 + l15] = az[gt][0];
      }
    }
    // G -> A is INTRA-WAVE: no barrier needed
    FENCE_LGKM();

    // ======== Phase A: activations (exp2-folded), h_full -> HF (bf16) ========
    {
      const int d = tid;
      const float t0 = __builtin_fmaf(Graw[0*512 + d], DSC_L,  cxL[0]);
      const float t1 = __builtin_fmaf(Graw[1*512 + d], DSC_L,  cxL[1]);
      const float t2 = __builtin_fmaf(Graw[2*512 + d], DSC_L2, cxL[2]);
      const float t3 = __builtin_fmaf(Graw[3*512 + d], DSC_L,  cxL[3]);
      const float iv = rcpf(1.f + exp2f(-t0));
      const float fv = rcpf(1.f + exp2f(-t1));
      const float gg = __builtin_fmaf(-2.f, rcpf(exp2f(t2) + 1.f), 1.f);
      const float ov = rcpf(1.f + exp2f(-t3));
      const float cc = __builtin_fmaf(fv, c_st, iv*gg);
      c_st = cc;
      const float tc = __builtin_fmaf(-2.f, rcpf(exp2f(cc*(2.f*L2E)) + 1.f), 1.f);
      HF[d] = __float2bfloat16(ov * tc);
    }
    BAR_LGKM();  // Bar2: HF ready (cross-wave); no vmcnt drain

    // ======== Phase R: h = h_full · W_hr^T (bf16; B: 10 frags regs + 6 LDS) ========
    if (s+1 < S_ && tid < 16)
      A8[128 + tid] = f2fp8(ASCALE * xv);                 // x(s+1), safe post-Bar2

    f32x4 aA = zz, aB = zz;
    #pragma unroll
    for (int kk=0; kk<16; ++kk){
      bf16x8 a2 = ldg8(&HF[hf_off + kk*32]);
      bf16x8 b2;
      if (kk < 10) b2 = __builtin_bit_cast(bf16x8, wrr[kk]);
      else         b2 = ldg8(&Wr2L[((w*6 + (kk-10))*64 + l)*8]);
      if (kk & 1) aB = __builtin_amdgcn_mfma_f32_16x16x32_bf16(a2, b2, aB, 0,0,0);
      else        aA = __builtin_amdgcn_mfma_f32_16x16x32_bf16(a2, b2, aA, 0,0,0);
    }
    f32x4 acc2 = aA + aB;    // row 0 (lq==0) = batch, col p = w*16+l15

    // raw h -> A8 (fp8 recurrent state) and HN (bf16 for heads/LN moments)
    if (lq == 0){
      const float h = acc2[0];
      HN[w*16 + l15] = __float2bfloat16(h);
      A8[w*16 + l15] = f2fp8(ASCALE * h);
    }
    BAR_LGKM();  // Bar3: A8/HN ready for next step (cross-wave); no vmcnt drain
  }

  // ======== epilogue: heads for s = S_-1 (wave 7) ========
  if (w == 7){
    f32x4 hd = zz, ss = zz;
    #pragma unroll
    for (int kc=0;kc<4;++kc){
      bf16x8 ha = ldg8(&HN[hn_off + kc*32]);
      bf16x8 hb = ldg8(&Wh2L[(kc*64 + l)*8]);
      hd = __builtin_amdgcn_mfma_f32_16x16x32_bf16(ha, hb, hd, 0,0,0);
      ss = __builtin_amdgcn_mfma_f32_16x16x32_bf16(ha, ha, ss, 0,0,0);
    }
    const float sh = __shfl(hd[0], 14);
    const float s2 = __shfl(ss[0], 0);
    const float m  = sh * (1.f/128.f);
    const float vr = s2 * (1.f/128.f) - m*m;
    const float rs = rsqrtf(vr + 1e-5f);
    if (lq == 0){
      const float v = rs*(hd[0] - m*S1k) + S2k;
      if (l15 < 6)       out_cmd[(b0*S_ + (S_-1))*6 + l15] = v;
      else if (l15 < 14) out_coord[(b0*S_ + (S_-1))*8 + (l15-6)] = v;
    }
  }
}

extern "C" void kernel_launch(void* const* d_in, const int* in_sizes, int n_in,
                              void* d_out, int out_size, void* d_ws, size_t ws_size,
                              hipStream_t stream)
{
  const float* x_std       = (const float*)d_in[0];
  const float* context     = (const float*)d_in[1];
  const float* W_cmd       = (const float*)d_in[2];
  const float* b_cmd       = (const float*)d_in[3];
  const float* W_coord     = (const float*)d_in[4];
  const float* b_coord     = (const float*)d_in[5];
  const float* W_head      = (const float*)d_in[6];
  const float* b_head      = (const float*)d_in[7];
  const float* W_ih        = (const float*)d_in[8];
  const float* W_hh        = (const float*)d_in[9];
  const float* W_hr        = (const float*)d_in[10];
  const float* b_ih        = (const float*)d_in[11];
  const float* b_hh        = (const float*)d_in[12];
  const float* ln_g        = (const float*)d_in[13];
  const float* ln_b        = (const float*)d_in[14];
  const float* W_out_cmd   = (const float*)d_in[15];
  const float* b_out_cmd   = (const float*)d_in[16];
  const float* W_out_coord = (const float*)d_in[17];
  const float* b_out_coord = (const float*)d_in[18];

  float* out = (float*)d_out;
  char*  ws  = (char*)d_ws;

  unsigned char*  Bp_s = (unsigned char*)(ws);              // 262144
  unsigned char*  Bp4  = (unsigned char*)(ws + 262144);     // 65536  -> 327680
  __hip_bfloat16* Wr2  = (__hip_bfloat16*)(ws + 327680);    // 131072 -> 458752
  __hip_bfloat16* Wh2  = (__hip_bfloat16*)(ws + 458752);    // 4096   -> 462848
  float* S12           = (float*)(ws + 462848);             // 128    -> 462976
  float* b_fold        = (float*)(ws + 462976);             // 8192   -> 471168
  float* W_comb        = (float*)(ws + 471168);             // 131072 -> 602240
  float* ctxB          = (float*)(ws + 602240);             // 2097152 -> 2699392 total

  k_fold<<<dim3(G4), dim3(64), 0, stream>>>(W_ih, W_cmd, b_cmd, W_coord, b_coord,
                                            W_head, b_head, W_comb, b_fold);
  k_bp<<<dim3(1280), dim3(256), 0, stream>>>(W_hh, W_comb, Bp_s, Bp4);
  k_wr2<<<dim3(256), dim3(256), 0, stream>>>(W_hr, Wr2);
  k_wh2<<<dim3(9), dim3(256), 0, stream>>>(ln_g, ln_b, W_out_cmd, W_out_coord,
                                           b_out_cmd, b_out_coord, Wh2, S12);
  k_ctx<<<dim3((B_*G4)/256), dim3(256), 0, stream>>>(context, W_ih, b_ih, b_hh,
                                                     b_fold, ctxB);
  k_scan<<<dim3(B_/NB), dim3(512), 0, stream>>>(x_std, ctxB, Bp_s, Bp4, Wr2, Wh2, S12,
                                                out, out + B_*S_*6);
}